// Round 11
// baseline (140.287 us; speedup 1.0000x reference)
//
#include <hip/hip_runtime.h>
#include <hip/hip_bf16.h>
#include <math.h>

#define B_  8
#define N_  1024
#define H_  512
#define NH_ 8
#define HD_ 64

typedef __attribute__((ext_vector_type(8))) short short8;
typedef __attribute__((ext_vector_type(4))) short short4_t;
typedef __attribute__((ext_vector_type(4))) float floatx4;

#define GPTR(p) ((const __attribute__((address_space(1))) void*)(p))
#define LPTR(p) ((__attribute__((address_space(3))) void*)(p))

// ds_read_b64_tr_b16: lane l elem j <- lds[region + j*16 + (l&15)] (bf16 elems)
#define TRB16(dst, addr, IMM) \
    asm volatile("ds_read_b64_tr_b16 %0, %1 offset:" IMM \
                 : "=v"(dst) : "v"(addr) : "memory")

#define EXP2(x) exp2f(x)
#define LOG2E 1.44269504088896f

static __device__ __forceinline__ unsigned short f2bf(float f) {
    __hip_bfloat16 h = __float2bfloat16(f);
    unsigned short u;
    __builtin_memcpy(&u, &h, 2);
    return u;
}

// ---------------------------------------------------------------------------
// prep: [blocks 0,1280): fp32->bf16 blob [xb | Wq | Wk | Wv | Wo]
//       [blocks 1280,3328): bins[b][q][k] = mask ? 255 : clip(d*10,0,49)
// ---------------------------------------------------------------------------
__global__ __launch_bounds__(256) void prep_kernel(
    const float* __restrict__ x,  const float* __restrict__ wq,
    const float* __restrict__ wk, const float* __restrict__ wv,
    const float* __restrict__ wo, unsigned short* __restrict__ dst,
    const float* __restrict__ dist, const int* __restrict__ mask,
    unsigned char* __restrict__ bins)
{
    const int bid = blockIdx.x;
    if (bid < 1280) {
        const int n4 = (4194304 + 4 * 262144) / 4;
        int i = bid * 256 + threadIdx.x;
        for (; i < n4; i += 1280 * 256) {
            const int e = i * 4;
            const float* src;
            if (e < 4194304) {
                src = x + e;
            } else {
                const int rel = e - 4194304;
                const int w = rel >> 18;
                const int off = rel & 262143;
                src = (w == 0 ? wq : w == 1 ? wk : w == 2 ? wv : wo) + off;
            }
            const float4 v = *(const float4*)src;
            ushort4 r;
            r.x = f2bf(v.x); r.y = f2bf(v.y); r.z = f2bf(v.z); r.w = f2bf(v.w);
            *(ushort4*)(dst + e) = r;
        }
    } else {
        const int gid = (bid - 1280) * 256 + threadIdx.x;   // 524288 total
        const size_t e = (size_t)gid * 16;
        const int b = gid >> 16;
        const int k = (gid & 63) * 16;
        const float* dsrc = dist + e;
        const int*   msrc = mask + b * N_ + k;
        unsigned w[4];
        #pragma unroll
        for (int i = 0; i < 4; ++i) {
            const float4 v = *(const float4*)(dsrc + 4 * i);
            const int4  mm = *(const int4*)(msrc + 4 * i);
            int b0 = (int)(v.x * 10.f); b0 = b0 < 0 ? 0 : (b0 > 49 ? 49 : b0);
            int b1 = (int)(v.y * 10.f); b1 = b1 < 0 ? 0 : (b1 > 49 ? 49 : b1);
            int b2 = (int)(v.z * 10.f); b2 = b2 < 0 ? 0 : (b2 > 49 ? 49 : b2);
            int b3 = (int)(v.w * 10.f); b3 = b3 < 0 ? 0 : (b3 > 49 ? 49 : b3);
            if (mm.x) b0 = 255;
            if (mm.y) b1 = 255;
            if (mm.z) b2 = 255;
            if (mm.w) b3 = 255;
            w[i] = (unsigned)b0 | ((unsigned)b1 << 8) | ((unsigned)b2 << 16) | ((unsigned)b3 << 24);
        }
        uint4 u; u.x = w[0]; u.y = w[1]; u.z = w[2]; u.w = w[3];
        *(uint4*)(bins + e) = u;
    }
}

// ---------------------------------------------------------------------------
// MFMA GEMM (m97 structure), unchanged.
// ---------------------------------------------------------------------------
template <int BF16OUT>
static __device__ __forceinline__ void gemm_core(
    const unsigned short* __restrict__ A, const unsigned short* __restrict__ W,
    const float* __restrict__ bias, void* __restrict__ C,
    int Ncols, int K, float scale, int row0, int col0)
{
    __shared__ unsigned short As[128 * 32];
    __shared__ unsigned short Bs[128 * 32];

    const int t    = threadIdx.x;
    const int lane = t & 63;
    const int wave = t >> 6;
    const int wr   = wave >> 1;
    const int wc   = wave & 1;
    const int l15  = lane & 15;
    const int lhi  = lane >> 4;

    const int srow = wave * 32 + (lane >> 2);
    const int sk   = (lane & 3) * 8;
    const unsigned short* gA = A + (size_t)(row0 + srow) * K + sk;
    const unsigned short* gB = W + (size_t)(col0 + srow) * K + sk;

    floatx4 acc[4][4];
    #pragma unroll
    for (int m = 0; m < 4; ++m)
        #pragma unroll
        for (int n = 0; n < 4; ++n) acc[m][n] = (floatx4)0.f;

    for (int k0 = 0; k0 < K; k0 += 32) {
        __syncthreads();
        #pragma unroll
        for (int i = 0; i < 2; ++i) {
            __builtin_amdgcn_global_load_lds(GPTR(gA + (size_t)(i * 16) * K + k0),
                                             LPTR(&As[(wave * 32 + i * 16) * 32]), 16, 0, 0);
            __builtin_amdgcn_global_load_lds(GPTR(gB + (size_t)(i * 16) * K + k0),
                                             LPTR(&Bs[(wave * 32 + i * 16) * 32]), 16, 0, 0);
        }
        __syncthreads();

        short8 af[4], bf[4];
        #pragma unroll
        for (int m = 0; m < 4; ++m)
            af[m] = *(const short8*)&As[(wr * 64 + m * 16 + l15) * 32 + lhi * 8];
        #pragma unroll
        for (int n = 0; n < 4; ++n)
            bf[n] = *(const short8*)&Bs[(wc * 64 + n * 16 + l15) * 32 + lhi * 8];
        #pragma unroll
        for (int m = 0; m < 4; ++m)
            #pragma unroll
            for (int n = 0; n < 4; ++n)
                acc[m][n] = __builtin_amdgcn_mfma_f32_16x16x32_bf16(af[m], bf[n], acc[m][n], 0, 0, 0);
    }

    #pragma unroll
    for (int n = 0; n < 4; ++n) {
        const int col = col0 + wc * 64 + n * 16 + l15;
        const float bvv = bias[col];
        #pragma unroll
        for (int m = 0; m < 4; ++m) {
            #pragma unroll
            for (int r = 0; r < 4; ++r) {
                const int row = row0 + wr * 64 + m * 16 + lhi * 4 + r;
                const float v = (acc[m][n][r] + bvv) * scale;
                if (BF16OUT)
                    ((unsigned short*)C)[(size_t)row * Ncols + col] = f2bf(v);
                else
                    ((float*)C)[(size_t)row * Ncols + col] = v;
            }
        }
    }
}

__global__ __launch_bounds__(256) void gemm_qkv(
    const unsigned short* __restrict__ xb,
    const unsigned short* __restrict__ Wq, const unsigned short* __restrict__ Wk,
    const unsigned short* __restrict__ Wv,
    const float* __restrict__ bq, const float* __restrict__ bk,
    const float* __restrict__ bv,
    unsigned short* __restrict__ Qb, unsigned short* __restrict__ Kb,
    unsigned short* __restrict__ Vb)
{
    const int z = blockIdx.z;
    const unsigned short* W = z == 0 ? Wq : (z == 1 ? Wk : Wv);
    const float* bias       = z == 0 ? bq : (z == 1 ? bk : bv);
    unsigned short* C       = z == 0 ? Qb : (z == 1 ? Kb : Vb);
    const float scale       = z == 0 ? (0.125f * LOG2E) : 1.0f;
    gemm_core<1>(xb, W, bias, C, H_, H_, scale, blockIdx.y * 128, blockIdx.x * 128);
}

__global__ __launch_bounds__(256) void gemm_out(
    const unsigned short* __restrict__ Ab, const unsigned short* __restrict__ Wo,
    const float* __restrict__ bo, float* __restrict__ out)
{
    gemm_core<0>(Ab, Wo, bo, out, H_, H_, 1.0f, blockIdx.y * 128, blockIdx.x * 128);
}

// ---------------------------------------------------------------------------
// MFMA flash attention — swapped-QK^T + direct-global bins + defer-max.
//  - bins read per-lane from global (L2-resident), next tile prefetched in
//    4 VGPRs; Bs LDS buffer deleted (LDS 24.6KB).
//  - defer-max (THR=8, exp2 domain): skip alpha-rescale while tile max
//    stays within 8 of running max (wave-uniform branch).
//  - rest identical to R10 (lane-local softmax, P b64/b128, gload_lds K/V).
// ---------------------------------------------------------------------------
__global__ __launch_bounds__(256) void attn_mfma(
    const unsigned short* __restrict__ Qg, const unsigned short* __restrict__ Kg,
    const unsigned short* __restrict__ Vg, const unsigned char* __restrict__ bins,
    const float* __restrict__ demb, const float* __restrict__ abias,
    unsigned short* __restrict__ O)
{
    const int qt = blockIdx.x;
    const int h  = blockIdx.y;
    const int b  = blockIdx.z;
    const int q0 = qt * 64;
    const int t  = threadIdx.x;
    const int lane = t & 63;
    const int wave = t >> 6;
    const int l15 = lane & 15;
    const int lhi = lane >> 4;

    __shared__ unsigned short Ks[64 * 64];   // XOR-swizzled rows (linear dest)
    __shared__ unsigned short Vs[64 * 64];   // [d/16][k/4][4][16] subtiled
    __shared__ unsigned short QPs[64 * 64];  // prologue: Q; loop: per-wave P

    // lane-register bias table (log2e domain); lane 63 = masked (-1.44e9)
    float dbl = -1.442695e9f;
    if (lane < 50) dbl = (demb[lane * NH_ + h] + abias[h]) * LOG2E;

    // ---- per-lane staging sources (pre-swizzled for linear LDS dest) ----
    const unsigned short* ksrc[2];
    const unsigned short* vsrc[2];
    #pragma unroll
    for (int i = 0; i < 2; ++i) {
        const int C = wave * 128 + i * 64 + lane;   // LDS 16B-chunk index
        const int kr = C >> 3, c = C & 7;
        ksrc[i] = Kg + ((size_t)(b * N_) + kr) * H_ + h * HD_ + ((c ^ (kr & 7)) * 8);
        const int vd16 = C >> 7, rem = C & 127;
        const int krhi = rem >> 3, r2 = rem & 7;
        const int vkr = krhi * 4 + (r2 >> 1), vc = r2 & 1;
        vsrc[i] = Vg + ((size_t)(b * N_) + vkr) * H_ + h * HD_ + vd16 * 16 + vc * 8;
    }
    // bins: lane reads its own row q = q0 + wave*16 + l15, cols lhi*4 + kn*16
    const unsigned char* bbase =
        bins + ((size_t)(b * N_) + q0 + (wave << 4) + l15) * N_ + (lhi << 2);

    // ---- stage Q (pre-scaled by 0.125*log2e), XOR-swizzled ----
    {
        const int qr = t >> 2;
        const int d0 = (t & 3) * 16;
        const unsigned short* src = Qg + ((size_t)(b * N_ + q0 + qr)) * H_ + h * HD_ + d0;
        #pragma unroll
        for (int cc = 0; cc < 2; ++cc) {
            const uint4 v = *(const uint4*)(src + 8 * cc);
            const int idx = (qr * 64 + d0 + 8 * cc) ^ ((qr & 7) << 3);
            *(uint4*)&QPs[idx] = v;
        }
    }
    // tile-0 bins prefetch (overlaps Q-stage latency)
    unsigned brC[4], brN[4];
    #pragma unroll
    for (int kn = 0; kn < 4; ++kn)
        brC[kn] = *(const unsigned*)(bbase + kn * 16);
    __syncthreads();

    // Q fragment (B-operand of swapped QK^T; constant over k-tiles)
    short8 aq[2];
    {
        const int qrow = (wave << 4) + l15;
        #pragma unroll
        for (int ck = 0; ck < 2; ++ck) {
            const int kb = lhi * 8 + 32 * ck;
            const int idx = (qrow * 64 + kb) ^ ((qrow & 7) << 3);
            aq[ck] = *(const short8*)&QPs[idx];
        }
    }
    __syncthreads();   // aq reads drained before QPs reused as P

    unsigned short* const Pw = &QPs[wave << 10];   // per-wave 2KB P region
    const unsigned trlane = (unsigned)(lhi << 8) + (unsigned)(l15 << 3);
    const unsigned vaddr = (unsigned)(size_t)LPTR(&Vs[0]) + trlane;

    // per-lane softmax state for q = l15 (replicated across lhi groups)
    float m = -INFINITY, lsum = 0.f;
    floatx4 o4[4];
    #pragma unroll
    for (int nd = 0; nd < 4; ++nd) o4[nd] = (floatx4)0.f;

    for (int tt = 0; tt < 16; ++tt) {
        const int k0 = tt * 64;
        __syncthreads();   // previous tile's reads done
        {
            const size_t koff = (size_t)k0;
            #pragma unroll
            for (int i = 0; i < 2; ++i) {
                __builtin_amdgcn_global_load_lds(GPTR(ksrc[i] + koff * H_),
                    LPTR(&Ks[(wave * 128 + i * 64) * 8]), 16, 0, 0);
                __builtin_amdgcn_global_load_lds(GPTR(vsrc[i] + koff * H_),
                    LPTR(&Vs[(wave * 128 + i * 64) * 8]), 16, 0, 0);
            }
        }
        // next tile's bins -> 4 VGPRs (L2 latency hides under compute)
        if (tt < 15) {
            #pragma unroll
            for (int kn = 0; kn < 4; ++kn)
                brN[kn] = *(const unsigned*)(bbase + (tt + 1) * 64 + kn * 16);
        }
        __syncthreads();   // staging drained

        // ---- S^T = K (Q*0.125*log2e)^T : s4[kn][r] = S[q=l15][k=kn*16+lhi*4+r]
        floatx4 s4[4];
        __builtin_amdgcn_s_setprio(1);
        #pragma unroll
        for (int kn = 0; kn < 4; ++kn) {
            const int kcol = kn * 16 + l15;
            floatx4 acc = (floatx4)0.f;
            #pragma unroll
            for (int ck = 0; ck < 2; ++ck) {
                const int kb = lhi * 8 + 32 * ck;
                const int idx = (kcol * 64 + kb) ^ ((kcol & 7) << 3);
                const short8 bk = *(const short8*)&Ks[idx];
                acc = __builtin_amdgcn_mfma_f32_16x16x32_bf16(bk, aq[ck], acc, 0, 0, 0);
            }
            s4[kn] = acc;
        }
        __builtin_amdgcn_s_setprio(0);

        // ---- + distance bias from registers (lane-table shuffle) ----
        #pragma unroll
        for (int kn = 0; kn < 4; ++kn) {
            const unsigned bb = brC[kn];
            s4[kn][0] += __shfl(dbl, (int)(bb & 255u), 64);
            s4[kn][1] += __shfl(dbl, (int)((bb >> 8) & 255u), 64);
            s4[kn][2] += __shfl(dbl, (int)((bb >> 16) & 255u), 64);
            s4[kn][3] += __shfl(dbl, (int)(bb >> 24), 64);
        }
        #pragma unroll
        for (int kn = 0; kn < 4; ++kn) brC[kn] = brN[kn];

        // ---- online softmax: lane-local + defer-max (THR=8, exp2 domain) ----
        {
            float mx = s4[0][0];
            #pragma unroll
            for (int kn = 0; kn < 4; ++kn)
                #pragma unroll
                for (int r = 0; r < 4; ++r) mx = fmaxf(mx, s4[kn][r]);
            mx = fmaxf(mx, __shfl_xor(mx, 16, 64));
            mx = fmaxf(mx, __shfl_xor(mx, 32, 64));

            if (__all(mx <= m + 8.f)) {
                // stable: keep m, no rescale; P bounded by 2^8
                float ts = 0.f;
                #pragma unroll
                for (int kn = 0; kn < 4; ++kn)
                    #pragma unroll
                    for (int r = 0; r < 4; ++r) {
                        const float p = EXP2(s4[kn][r] - m);
                        s4[kn][r] = p;
                        ts += p;
                    }
                ts += __shfl_xor(ts, 16, 64);
                ts += __shfl_xor(ts, 32, 64);
                lsum += ts;
            } else {
                const float mnew = fmaxf(m, mx);
                float ts = 0.f;
                #pragma unroll
                for (int kn = 0; kn < 4; ++kn)
                    #pragma unroll
                    for (int r = 0; r < 4; ++r) {
                        const float p = EXP2(s4[kn][r] - mnew);
                        s4[kn][r] = p;
                        ts += p;
                    }
                ts += __shfl_xor(ts, 16, 64);
                ts += __shfl_xor(ts, 32, 64);
                const float alpha = EXP2(m - mnew);
                lsum = lsum * alpha + ts;
                m = mnew;
                #pragma unroll
                for (int r = 0; r < 4; ++r) {
                    const float ar = __shfl(alpha, lhi * 4 + r, 64);
                    #pragma unroll
                    for (int nd = 0; nd < 4; ++nd) o4[nd][r] *= ar;
                }
            }
        }

        // ---- P[q=l15][k] -> LDS: 4 b64 writes at contiguous k ----
        #pragma unroll
        for (int kn = 0; kn < 4; ++kn) {
            short4_t pk;
            pk[0] = (short)f2bf(s4[kn][0]);
            pk[1] = (short)f2bf(s4[kn][1]);
            pk[2] = (short)f2bf(s4[kn][2]);
            pk[3] = (short)f2bf(s4[kn][3]);
            const int idx = (l15 * 64 + kn * 16 + (lhi << 2)) ^ ((l15 & 7) << 3);
            *(short4_t*)&Pw[idx] = pk;
        }

        // ---- PV: A = 2 direct b128 P reads; B = 16 V tr-reads ----
        short8 ap[2];
        #pragma unroll
        for (int ck = 0; ck < 2; ++ck) {
            const int idx = (l15 * 64 + ck * 32 + lhi * 8) ^ ((l15 & 7) << 3);
            ap[ck] = *(const short8*)&Pw[idx];
        }
        short4_t v0l[4], v0h[4], v1l[4], v1h[4];
        TRB16(v0l[0], vaddr, "0");    TRB16(v0h[0], vaddr, "128");
        TRB16(v0l[1], vaddr, "2048"); TRB16(v0h[1], vaddr, "2176");
        TRB16(v0l[2], vaddr, "4096"); TRB16(v0h[2], vaddr, "4224");
        TRB16(v0l[3], vaddr, "6144"); TRB16(v0h[3], vaddr, "6272");
        TRB16(v1l[0], vaddr, "1024"); TRB16(v1h[0], vaddr, "1152");
        TRB16(v1l[1], vaddr, "3072"); TRB16(v1h[1], vaddr, "3200");
        TRB16(v1l[2], vaddr, "5120"); TRB16(v1h[2], vaddr, "5248");
        TRB16(v1l[3], vaddr, "7168"); TRB16(v1h[3], vaddr, "7296");
        asm volatile("s_waitcnt lgkmcnt(0)" ::: "memory");
        __builtin_amdgcn_sched_barrier(0);

        __builtin_amdgcn_s_setprio(1);
        #pragma unroll
        for (int nd = 0; nd < 4; ++nd) {
            const short8 bv0 = __builtin_shufflevector(v0l[nd], v0h[nd], 0, 1, 2, 3, 4, 5, 6, 7);
            o4[nd] = __builtin_amdgcn_mfma_f32_16x16x32_bf16(ap[0], bv0, o4[nd], 0, 0, 0);
            const short8 bv1 = __builtin_shufflevector(v1l[nd], v1h[nd], 0, 1, 2, 3, 4, 5, 6, 7);
            o4[nd] = __builtin_amdgcn_mfma_f32_16x16x32_bf16(ap[1], bv1, o4[nd], 0, 0, 0);
        }
        __builtin_amdgcn_s_setprio(0);
    }

    // ---- epilogue: pull lsum for q=lhi*4+r, normalize, write ----
    float inv[4];
    #pragma unroll
    for (int r = 0; r < 4; ++r) inv[r] = 1.f / __shfl(lsum, lhi * 4 + r, 64);
    #pragma unroll
    for (int nd = 0; nd < 4; ++nd) {
        const int d = nd * 16 + l15;
        #pragma unroll
        for (int r = 0; r < 4; ++r) {
            const int q = q0 + (wave << 4) + lhi * 4 + r;
            O[((size_t)(b * N_ + q)) * H_ + h * HD_ + d] = f2bf(o4[nd][r] * inv[r]);
        }
    }
}

// ---------------------------------------------------------------------------
extern "C" void kernel_launch(void* const* d_in, const int* in_sizes, int n_in,
                              void* d_out, int out_size, void* d_ws, size_t ws_size,
                              hipStream_t stream)
{
    const float* x    = (const float*)d_in[0];
    const float* dist = (const float*)d_in[1];
    const int*   mask = (const int*)d_in[2];
    const float* Wq   = (const float*)d_in[3];
    const float* bq   = (const float*)d_in[4];
    const float* Wk   = (const float*)d_in[5];
    const float* bk   = (const float*)d_in[6];
    const float* Wv   = (const float*)d_in[7];
    const float* bv   = (const float*)d_in[8];
    const float* Wo   = (const float*)d_in[9];
    const float* bo   = (const float*)d_in[10];
    const float* demb = (const float*)d_in[11];
    const float* ab   = (const float*)d_in[12];
    float* out = (float*)d_out;

    const size_t mat = (size_t)B_ * N_ * H_;         // 4,194,304
    const size_t wsz = (size_t)H_ * H_;              //   262,144

    unsigned short* blob = (unsigned short*)d_ws;
    unsigned short* xb  = blob;
    unsigned short* Wqb = blob + mat;
    unsigned short* Wkb = Wqb + wsz;
    unsigned short* Wvb = Wkb + wsz;
    unsigned short* Wob = Wvb + wsz;
    unsigned short* Qb  = Wob + wsz;
    unsigned short* Kb  = Qb + mat;
    unsigned short* Vb  = Kb + mat;
    unsigned short* Ab  = Vb + mat;
    unsigned char*  binsb = (unsigned char*)(Ab + mat);

    const dim3 blk(256);

    hipLaunchKernelGGL(prep_kernel, dim3(3328), blk, 0, stream,
                       x, Wq, Wk, Wv, Wo, blob, dist, mask, binsb);

    const dim3 qgrid(H_ / 128, (B_ * N_) / 128, 3);
    hipLaunchKernelGGL(gemm_qkv, qgrid, blk, 0, stream,
                       xb, Wqb, Wkb, Wvb, bq, bk, bv, Qb, Kb, Vb);

    const dim3 agrid(N_ / 64, NH_, B_);
    hipLaunchKernelGGL(attn_mfma, agrid, blk, 0, stream,
                       Qb, Kb, Vb, binsb, demb, ab, Ab);

    const dim3 ogrid(H_ / 128, (B_ * N_) / 128, 1);
    hipLaunchKernelGGL(gemm_out, ogrid, blk, 0, stream, Ab, Wob, bo, out);
}

// Round 12
// 126.246 us; speedup vs baseline: 1.1112x; 1.1112x over previous
//
#include <hip/hip_runtime.h>
#include <hip/hip_bf16.h>
#include <math.h>

#define B_  8
#define N_  1024
#define H_  512
#define NH_ 8
#define HD_ 64

typedef __attribute__((ext_vector_type(8))) short short8;
typedef __attribute__((ext_vector_type(4))) short short4_t;
typedef __attribute__((ext_vector_type(4))) float floatx4;

#define GPTR(p) ((const __attribute__((address_space(1))) void*)(p))
#define LPTR(p) ((__attribute__((address_space(3))) void*)(p))

// ds_read_b64_tr_b16: lane l elem j <- lds[region + j*16 + (l&15)] (bf16 elems)
#define TRB16(dst, addr, IMM) \
    asm volatile("ds_read_b64_tr_b16 %0, %1 offset:" IMM \
                 : "=v"(dst) : "v"(addr) : "memory")

#define EXP2(x) exp2f(x)
#define LOG2E 1.44269504088896f

static __device__ __forceinline__ unsigned short f2bf(float f) {
    __hip_bfloat16 h = __float2bfloat16(f);
    unsigned short u;
    __builtin_memcpy(&u, &h, 2);
    return u;
}

// ---------------------------------------------------------------------------
// prep: [blocks 0,1280): fp32->bf16 blob [xb | Wq | Wk | Wv | Wo]
//       [blocks 1280,3328): bins[b][q][k] = mask ? 255 : clip(d*10,0,49)
// ---------------------------------------------------------------------------
__global__ __launch_bounds__(256) void prep_kernel(
    const float* __restrict__ x,  const float* __restrict__ wq,
    const float* __restrict__ wk, const float* __restrict__ wv,
    const float* __restrict__ wo, unsigned short* __restrict__ dst,
    const float* __restrict__ dist, const int* __restrict__ mask,
    unsigned char* __restrict__ bins)
{
    const int bid = blockIdx.x;
    if (bid < 1280) {
        const int n4 = (4194304 + 4 * 262144) / 4;
        int i = bid * 256 + threadIdx.x;
        for (; i < n4; i += 1280 * 256) {
            const int e = i * 4;
            const float* src;
            if (e < 4194304) {
                src = x + e;
            } else {
                const int rel = e - 4194304;
                const int w = rel >> 18;
                const int off = rel & 262143;
                src = (w == 0 ? wq : w == 1 ? wk : w == 2 ? wv : wo) + off;
            }
            const float4 v = *(const float4*)src;
            ushort4 r;
            r.x = f2bf(v.x); r.y = f2bf(v.y); r.z = f2bf(v.z); r.w = f2bf(v.w);
            *(ushort4*)(dst + e) = r;
        }
    } else {
        const int gid = (bid - 1280) * 256 + threadIdx.x;   // 524288 total
        const size_t e = (size_t)gid * 16;
        const int b = gid >> 16;
        const int k = (gid & 63) * 16;
        const float* dsrc = dist + e;
        const int*   msrc = mask + b * N_ + k;
        unsigned w[4];
        #pragma unroll
        for (int i = 0; i < 4; ++i) {
            const float4 v = *(const float4*)(dsrc + 4 * i);
            const int4  mm = *(const int4*)(msrc + 4 * i);
            int b0 = (int)(v.x * 10.f); b0 = b0 < 0 ? 0 : (b0 > 49 ? 49 : b0);
            int b1 = (int)(v.y * 10.f); b1 = b1 < 0 ? 0 : (b1 > 49 ? 49 : b1);
            int b2 = (int)(v.z * 10.f); b2 = b2 < 0 ? 0 : (b2 > 49 ? 49 : b2);
            int b3 = (int)(v.w * 10.f); b3 = b3 < 0 ? 0 : (b3 > 49 ? 49 : b3);
            if (mm.x) b0 = 255;
            if (mm.y) b1 = 255;
            if (mm.z) b2 = 255;
            if (mm.w) b3 = 255;
            w[i] = (unsigned)b0 | ((unsigned)b1 << 8) | ((unsigned)b2 << 16) | ((unsigned)b3 << 24);
        }
        uint4 u; u.x = w[0]; u.y = w[1]; u.z = w[2]; u.w = w[3];
        *(uint4*)(bins + e) = u;
    }
}

// ---------------------------------------------------------------------------
// MFMA GEMM (m97 structure), unchanged.
// ---------------------------------------------------------------------------
template <int BF16OUT>
static __device__ __forceinline__ void gemm_core(
    const unsigned short* __restrict__ A, const unsigned short* __restrict__ W,
    const float* __restrict__ bias, void* __restrict__ C,
    int Ncols, int K, float scale, int row0, int col0)
{
    __shared__ unsigned short As[128 * 32];
    __shared__ unsigned short Bs[128 * 32];

    const int t    = threadIdx.x;
    const int lane = t & 63;
    const int wave = t >> 6;
    const int wr   = wave >> 1;
    const int wc   = wave & 1;
    const int l15  = lane & 15;
    const int lhi  = lane >> 4;

    const int srow = wave * 32 + (lane >> 2);
    const int sk   = (lane & 3) * 8;
    const unsigned short* gA = A + (size_t)(row0 + srow) * K + sk;
    const unsigned short* gB = W + (size_t)(col0 + srow) * K + sk;

    floatx4 acc[4][4];
    #pragma unroll
    for (int m = 0; m < 4; ++m)
        #pragma unroll
        for (int n = 0; n < 4; ++n) acc[m][n] = (floatx4)0.f;

    for (int k0 = 0; k0 < K; k0 += 32) {
        __syncthreads();
        #pragma unroll
        for (int i = 0; i < 2; ++i) {
            __builtin_amdgcn_global_load_lds(GPTR(gA + (size_t)(i * 16) * K + k0),
                                             LPTR(&As[(wave * 32 + i * 16) * 32]), 16, 0, 0);
            __builtin_amdgcn_global_load_lds(GPTR(gB + (size_t)(i * 16) * K + k0),
                                             LPTR(&Bs[(wave * 32 + i * 16) * 32]), 16, 0, 0);
        }
        __syncthreads();

        short8 af[4], bf[4];
        #pragma unroll
        for (int m = 0; m < 4; ++m)
            af[m] = *(const short8*)&As[(wr * 64 + m * 16 + l15) * 32 + lhi * 8];
        #pragma unroll
        for (int n = 0; n < 4; ++n)
            bf[n] = *(const short8*)&Bs[(wc * 64 + n * 16 + l15) * 32 + lhi * 8];
        #pragma unroll
        for (int m = 0; m < 4; ++m)
            #pragma unroll
            for (int n = 0; n < 4; ++n)
                acc[m][n] = __builtin_amdgcn_mfma_f32_16x16x32_bf16(af[m], bf[n], acc[m][n], 0, 0, 0);
    }

    #pragma unroll
    for (int n = 0; n < 4; ++n) {
        const int col = col0 + wc * 64 + n * 16 + l15;
        const float bvv = bias[col];
        #pragma unroll
        for (int m = 0; m < 4; ++m) {
            #pragma unroll
            for (int r = 0; r < 4; ++r) {
                const int row = row0 + wr * 64 + m * 16 + lhi * 4 + r;
                const float v = (acc[m][n][r] + bvv) * scale;
                if (BF16OUT)
                    ((unsigned short*)C)[(size_t)row * Ncols + col] = f2bf(v);
                else
                    ((float*)C)[(size_t)row * Ncols + col] = v;
            }
        }
    }
}

__global__ __launch_bounds__(256) void gemm_qkv(
    const unsigned short* __restrict__ xb,
    const unsigned short* __restrict__ Wq, const unsigned short* __restrict__ Wk,
    const unsigned short* __restrict__ Wv,
    const float* __restrict__ bq, const float* __restrict__ bk,
    const float* __restrict__ bv,
    unsigned short* __restrict__ Qb, unsigned short* __restrict__ Kb,
    unsigned short* __restrict__ Vb)
{
    const int z = blockIdx.z;
    const unsigned short* W = z == 0 ? Wq : (z == 1 ? Wk : Wv);
    const float* bias       = z == 0 ? bq : (z == 1 ? bk : bv);
    unsigned short* C       = z == 0 ? Qb : (z == 1 ? Kb : Vb);
    const float scale       = z == 0 ? (0.125f * LOG2E) : 1.0f;
    gemm_core<1>(xb, W, bias, C, H_, H_, scale, blockIdx.y * 128, blockIdx.x * 128);
}

__global__ __launch_bounds__(256) void gemm_out(
    const unsigned short* __restrict__ Ab, const unsigned short* __restrict__ Wo,
    const float* __restrict__ bo, float* __restrict__ out)
{
    gemm_core<0>(Ab, Wo, bo, out, H_, H_, 1.0f, blockIdx.y * 128, blockIdx.x * 128);
}

// ---------------------------------------------------------------------------
// MFMA flash attention — swapped-QK^T + defer-max; bins staged via LDS
// (R10 structure; R11's uncoalesced direct-global bins reverted).
// ---------------------------------------------------------------------------
__global__ __launch_bounds__(256) void attn_mfma(
    const unsigned short* __restrict__ Qg, const unsigned short* __restrict__ Kg,
    const unsigned short* __restrict__ Vg, const unsigned char* __restrict__ bins,
    const float* __restrict__ demb, const float* __restrict__ abias,
    unsigned short* __restrict__ O)
{
    const int qt = blockIdx.x;
    const int h  = blockIdx.y;
    const int b  = blockIdx.z;
    const int q0 = qt * 64;
    const int t  = threadIdx.x;
    const int lane = t & 63;
    const int wave = t >> 6;
    const int l15 = lane & 15;
    const int lhi = lane >> 4;

    __shared__ unsigned short Ks[64 * 64];   // XOR-swizzled rows (linear dest)
    __shared__ unsigned short Vs[64 * 64];   // [d/16][k/4][4][16] subtiled
    __shared__ unsigned short QPs[64 * 64];  // prologue: Q; loop: per-wave P
    __shared__ unsigned char  Bs[64 * 80];   // [q][k] bins tile, stride 80

    // lane-register bias table (log2e domain); lane 63 = masked (-1.44e9)
    float dbl = -1.442695e9f;
    if (lane < 50) dbl = (demb[lane * NH_ + h] + abias[h]) * LOG2E;

    // ---- per-lane staging sources (pre-swizzled for linear LDS dest) ----
    const unsigned short* ksrc[2];
    const unsigned short* vsrc[2];
    #pragma unroll
    for (int i = 0; i < 2; ++i) {
        const int C = wave * 128 + i * 64 + lane;   // LDS 16B-chunk index
        const int kr = C >> 3, c = C & 7;
        ksrc[i] = Kg + ((size_t)(b * N_) + kr) * H_ + h * HD_ + ((c ^ (kr & 7)) * 8);
        const int vd16 = C >> 7, rem = C & 127;
        const int krhi = rem >> 3, r2 = rem & 7;
        const int vkr = krhi * 4 + (r2 >> 1), vc = r2 & 1;
        vsrc[i] = Vg + ((size_t)(b * N_) + vkr) * H_ + h * HD_ + vd16 * 16 + vc * 8;
    }
    const unsigned char* bsrc = bins + ((size_t)(b * N_) + q0 + (t >> 2)) * N_ + (t & 3) * 16;
    const int bidx = (t >> 2) * 80 + (t & 3) * 16;

    // ---- stage Q (pre-scaled by 0.125*log2e), XOR-swizzled ----
    {
        const int qr = t >> 2;
        const int d0 = (t & 3) * 16;
        const unsigned short* src = Qg + ((size_t)(b * N_ + q0 + qr)) * H_ + h * HD_ + d0;
        #pragma unroll
        for (int cc = 0; cc < 2; ++cc) {
            const uint4 v = *(const uint4*)(src + 8 * cc);
            const int idx = (qr * 64 + d0 + 8 * cc) ^ ((qr & 7) << 3);
            *(uint4*)&QPs[idx] = v;
        }
    }
    __syncthreads();

    // Q fragment (B-operand of swapped QK^T; constant over k-tiles)
    short8 aq[2];
    {
        const int qrow = (wave << 4) + l15;
        #pragma unroll
        for (int ck = 0; ck < 2; ++ck) {
            const int kb = lhi * 8 + 32 * ck;
            const int idx = (qrow * 64 + kb) ^ ((qrow & 7) << 3);
            aq[ck] = *(const short8*)&QPs[idx];
        }
    }
    __syncthreads();   // aq reads drained before QPs reused as P

    unsigned short* const Pw = &QPs[wave << 10];   // per-wave 2KB P region
    const unsigned trlane = (unsigned)(lhi << 8) + (unsigned)(l15 << 3);
    const unsigned vaddr = (unsigned)(size_t)LPTR(&Vs[0]) + trlane;

    // per-lane softmax state for q = l15 (replicated across lhi groups)
    float m = -INFINITY, lsum = 0.f;
    floatx4 o4[4];
    #pragma unroll
    for (int nd = 0; nd < 4; ++nd) o4[nd] = (floatx4)0.f;

    for (int k0 = 0; k0 < N_; k0 += 64) {
        __syncthreads();   // previous tile's reads done
        {
            const size_t koff = (size_t)k0;
            #pragma unroll
            for (int i = 0; i < 2; ++i) {
                __builtin_amdgcn_global_load_lds(GPTR(ksrc[i] + koff * H_),
                    LPTR(&Ks[(wave * 128 + i * 64) * 8]), 16, 0, 0);
                __builtin_amdgcn_global_load_lds(GPTR(vsrc[i] + koff * H_),
                    LPTR(&Vs[(wave * 128 + i * 64) * 8]), 16, 0, 0);
            }
            const uint4 brv = *(const uint4*)(bsrc + koff);
            *(uint4*)&Bs[bidx] = brv;
        }
        __syncthreads();   // staging drained

        // ---- S^T = K (Q*0.125*log2e)^T : s4[kn][r] = S[q=l15][k=kn*16+lhi*4+r]
        floatx4 s4[4];
        __builtin_amdgcn_s_setprio(1);
        #pragma unroll
        for (int kn = 0; kn < 4; ++kn) {
            const int kcol = kn * 16 + l15;
            floatx4 acc = (floatx4)0.f;
            #pragma unroll
            for (int ck = 0; ck < 2; ++ck) {
                const int kb = lhi * 8 + 32 * ck;
                const int idx = (kcol * 64 + kb) ^ ((kcol & 7) << 3);
                const short8 bk = *(const short8*)&Ks[idx];
                acc = __builtin_amdgcn_mfma_f32_16x16x32_bf16(bk, aq[ck], acc, 0, 0, 0);
            }
            s4[kn] = acc;
        }
        __builtin_amdgcn_s_setprio(0);

        // ---- + distance bias: row q=l15, contiguous k per kn ----
        #pragma unroll
        for (int kn = 0; kn < 4; ++kn) {
            const unsigned bb =
                *(const unsigned*)&Bs[((wave << 4) + l15) * 80 + kn * 16 + (lhi << 2)];
            s4[kn][0] += __shfl(dbl, (int)(bb & 255u), 64);
            s4[kn][1] += __shfl(dbl, (int)((bb >> 8) & 255u), 64);
            s4[kn][2] += __shfl(dbl, (int)((bb >> 16) & 255u), 64);
            s4[kn][3] += __shfl(dbl, (int)(bb >> 24), 64);
        }

        // ---- online softmax: lane-local + defer-max (THR=8, exp2 domain) ----
        {
            float mx = s4[0][0];
            #pragma unroll
            for (int kn = 0; kn < 4; ++kn)
                #pragma unroll
                for (int r = 0; r < 4; ++r) mx = fmaxf(mx, s4[kn][r]);
            mx = fmaxf(mx, __shfl_xor(mx, 16, 64));
            mx = fmaxf(mx, __shfl_xor(mx, 32, 64));

            if (__all(mx <= m + 8.f)) {
                // stable: keep m, no rescale; P bounded by 2^8
                float ts = 0.f;
                #pragma unroll
                for (int kn = 0; kn < 4; ++kn)
                    #pragma unroll
                    for (int r = 0; r < 4; ++r) {
                        const float p = EXP2(s4[kn][r] - m);
                        s4[kn][r] = p;
                        ts += p;
                    }
                ts += __shfl_xor(ts, 16, 64);
                ts += __shfl_xor(ts, 32, 64);
                lsum += ts;
            } else {
                const float mnew = fmaxf(m, mx);
                float ts = 0.f;
                #pragma unroll
                for (int kn = 0; kn < 4; ++kn)
                    #pragma unroll
                    for (int r = 0; r < 4; ++r) {
                        const float p = EXP2(s4[kn][r] - mnew);
                        s4[kn][r] = p;
                        ts += p;
                    }
                ts += __shfl_xor(ts, 16, 64);
                ts += __shfl_xor(ts, 32, 64);
                const float alpha = EXP2(m - mnew);
                lsum = lsum * alpha + ts;
                m = mnew;
                #pragma unroll
                for (int r = 0; r < 4; ++r) {
                    const float ar = __shfl(alpha, lhi * 4 + r, 64);
                    #pragma unroll
                    for (int nd = 0; nd < 4; ++nd) o4[nd][r] *= ar;
                }
            }
        }

        // ---- P[q=l15][k] -> LDS: 4 b64 writes at contiguous k ----
        #pragma unroll
        for (int kn = 0; kn < 4; ++kn) {
            short4_t pk;
            pk[0] = (short)f2bf(s4[kn][0]);
            pk[1] = (short)f2bf(s4[kn][1]);
            pk[2] = (short)f2bf(s4[kn][2]);
            pk[3] = (short)f2bf(s4[kn][3]);
            const int idx = (l15 * 64 + kn * 16 + (lhi << 2)) ^ ((l15 & 7) << 3);
            *(short4_t*)&Pw[idx] = pk;
        }

        // ---- PV: A = 2 direct b128 P reads; B = 16 V tr-reads ----
        short8 ap[2];
        #pragma unroll
        for (int ck = 0; ck < 2; ++ck) {
            const int idx = (l15 * 64 + ck * 32 + lhi * 8) ^ ((l15 & 7) << 3);
            ap[ck] = *(const short8*)&Pw[idx];
        }
        short4_t v0l[4], v0h[4], v1l[4], v1h[4];
        TRB16(v0l[0], vaddr, "0");    TRB16(v0h[0], vaddr, "128");
        TRB16(v0l[1], vaddr, "2048"); TRB16(v0h[1], vaddr, "2176");
        TRB16(v0l[2], vaddr, "4096"); TRB16(v0h[2], vaddr, "4224");
        TRB16(v0l[3], vaddr, "6144"); TRB16(v0h[3], vaddr, "6272");
        TRB16(v1l[0], vaddr, "1024"); TRB16(v1h[0], vaddr, "1152");
        TRB16(v1l[1], vaddr, "3072"); TRB16(v1h[1], vaddr, "3200");
        TRB16(v1l[2], vaddr, "5120"); TRB16(v1h[2], vaddr, "5248");
        TRB16(v1l[3], vaddr, "7168"); TRB16(v1h[3], vaddr, "7296");
        asm volatile("s_waitcnt lgkmcnt(0)" ::: "memory");
        __builtin_amdgcn_sched_barrier(0);

        __builtin_amdgcn_s_setprio(1);
        #pragma unroll
        for (int nd = 0; nd < 4; ++nd) {
            const short8 bv0 = __builtin_shufflevector(v0l[nd], v0h[nd], 0, 1, 2, 3, 4, 5, 6, 7);
            o4[nd] = __builtin_amdgcn_mfma_f32_16x16x32_bf16(ap[0], bv0, o4[nd], 0, 0, 0);
            const short8 bv1 = __builtin_shufflevector(v1l[nd], v1h[nd], 0, 1, 2, 3, 4, 5, 6, 7);
            o4[nd] = __builtin_amdgcn_mfma_f32_16x16x32_bf16(ap[1], bv1, o4[nd], 0, 0, 0);
        }
        __builtin_amdgcn_s_setprio(0);
    }

    // ---- epilogue: pull lsum for q=lhi*4+r, normalize, write ----
    float inv[4];
    #pragma unroll
    for (int r = 0; r < 4; ++r) inv[r] = 1.f / __shfl(lsum, lhi * 4 + r, 64);
    #pragma unroll
    for (int nd = 0; nd < 4; ++nd) {
        const int d = nd * 16 + l15;
        #pragma unroll
        for (int r = 0; r < 4; ++r) {
            const int q = q0 + (wave << 4) + lhi * 4 + r;
            O[((size_t)(b * N_ + q)) * H_ + h * HD_ + d] = f2bf(o4[nd][r] * inv[r]);
        }
    }
}

// ---------------------------------------------------------------------------
extern "C" void kernel_launch(void* const* d_in, const int* in_sizes, int n_in,
                              void* d_out, int out_size, void* d_ws, size_t ws_size,
                              hipStream_t stream)
{
    const float* x    = (const float*)d_in[0];
    const float* dist = (const float*)d_in[1];
    const int*   mask = (const int*)d_in[2];
    const float* Wq   = (const float*)d_in[3];
    const float* bq   = (const float*)d_in[4];
    const float* Wk   = (const float*)d_in[5];
    const float* bk   = (const float*)d_in[6];
    const float* Wv   = (const float*)d_in[7];
    const float* bv   = (const float*)d_in[8];
    const float* Wo   = (const float*)d_in[9];
    const float* bo   = (const float*)d_in[10];
    const float* demb = (const float*)d_in[11];
    const float* ab   = (const float*)d_in[12];
    float* out = (float*)d_out;

    const size_t mat = (size_t)B_ * N_ * H_;         // 4,194,304
    const size_t wsz = (size_t)H_ * H_;              //   262,144

    unsigned short* blob = (unsigned short*)d_ws;
    unsigned short* xb  = blob;
    unsigned short* Wqb = blob + mat;
    unsigned short* Wkb = Wqb + wsz;
    unsigned short* Wvb = Wkb + wsz;
    unsigned short* Wob = Wvb + wsz;
    unsigned short* Qb  = Wob + wsz;
    unsigned short* Kb  = Qb + mat;
    unsigned short* Vb  = Kb + mat;
    unsigned short* Ab  = Vb + mat;
    unsigned char*  binsb = (unsigned char*)(Ab + mat);

    const dim3 blk(256);

    hipLaunchKernelGGL(prep_kernel, dim3(3328), blk, 0, stream,
                       x, Wq, Wk, Wv, Wo, blob, dist, mask, binsb);

    const dim3 qgrid(H_ / 128, (B_ * N_) / 128, 3);
    hipLaunchKernelGGL(gemm_qkv, qgrid, blk, 0, stream,
                       xb, Wqb, Wkb, Wvb, bq, bk, bv, Qb, Kb, Vb);

    const dim3 agrid(N_ / 64, NH_, B_);
    hipLaunchKernelGGL(attn_mfma, agrid, blk, 0, stream,
                       Qb, Kb, Vb, binsb, demb, ab, Ab);

    const dim3 ogrid(H_ / 128, (B_ * N_) / 128, 1);
    hipLaunchKernelGGL(gemm_out, ogrid, blk, 0, stream, Ab, Wob, bo, out);
}

// Round 13
// 106.994 us; speedup vs baseline: 1.3112x; 1.1799x over previous
//
#include <hip/hip_runtime.h>
#include <hip/hip_bf16.h>
#include <math.h>

#define B_  8
#define N_  1024
#define H_  512
#define NH_ 8
#define HD_ 64

typedef __attribute__((ext_vector_type(8))) short short8;
typedef __attribute__((ext_vector_type(4))) short short4_t;
typedef __attribute__((ext_vector_type(4))) float floatx4;

#define GPTR(p) ((const __attribute__((address_space(1))) void*)(p))
#define LPTR(p) ((__attribute__((address_space(3))) void*)(p))

// ds_read_b64_tr_b16: lane l elem j <- lds[region + j*16 + (l&15)] (bf16 elems)
#define TRB16(dst, addr, IMM) \
    asm volatile("ds_read_b64_tr_b16 %0, %1 offset:" IMM \
                 : "=v"(dst) : "v"(addr) : "memory")

#define EXP2(x) exp2f(x)
#define LOG2E 1.44269504088896f

static __device__ __forceinline__ unsigned short f2bf(float f) {
    __hip_bfloat16 h = __float2bfloat16(f);
    unsigned short u;
    __builtin_memcpy(&u, &h, 2);
    return u;
}

// ---------------------------------------------------------------------------
// prep: [blocks 0,1280): fp32->bf16 blob [xb | Wq | Wk | Wv | Wo]
//       [blocks 1280,3328): bins[b][q][k] = mask ? 255 : clip(d*10,0,49)
// ---------------------------------------------------------------------------
__global__ __launch_bounds__(256) void prep_kernel(
    const float* __restrict__ x,  const float* __restrict__ wq,
    const float* __restrict__ wk, const float* __restrict__ wv,
    const float* __restrict__ wo, unsigned short* __restrict__ dst,
    const float* __restrict__ dist, const int* __restrict__ mask,
    unsigned char* __restrict__ bins)
{
    const int bid = blockIdx.x;
    if (bid < 1280) {
        const int n4 = (4194304 + 4 * 262144) / 4;
        int i = bid * 256 + threadIdx.x;
        for (; i < n4; i += 1280 * 256) {
            const int e = i * 4;
            const float* src;
            if (e < 4194304) {
                src = x + e;
            } else {
                const int rel = e - 4194304;
                const int w = rel >> 18;
                const int off = rel & 262143;
                src = (w == 0 ? wq : w == 1 ? wk : w == 2 ? wv : wo) + off;
            }
            const float4 v = *(const float4*)src;
            ushort4 r;
            r.x = f2bf(v.x); r.y = f2bf(v.y); r.z = f2bf(v.z); r.w = f2bf(v.w);
            *(ushort4*)(dst + e) = r;
        }
    } else {
        const int gid = (bid - 1280) * 256 + threadIdx.x;   // 524288 total
        const size_t e = (size_t)gid * 16;
        const int b = gid >> 16;
        const int k = (gid & 63) * 16;
        const float* dsrc = dist + e;
        const int*   msrc = mask + b * N_ + k;
        unsigned w[4];
        #pragma unroll
        for (int i = 0; i < 4; ++i) {
            const float4 v = *(const float4*)(dsrc + 4 * i);
            const int4  mm = *(const int4*)(msrc + 4 * i);
            int b0 = (int)(v.x * 10.f); b0 = b0 < 0 ? 0 : (b0 > 49 ? 49 : b0);
            int b1 = (int)(v.y * 10.f); b1 = b1 < 0 ? 0 : (b1 > 49 ? 49 : b1);
            int b2 = (int)(v.z * 10.f); b2 = b2 < 0 ? 0 : (b2 > 49 ? 49 : b2);
            int b3 = (int)(v.w * 10.f); b3 = b3 < 0 ? 0 : (b3 > 49 ? 49 : b3);
            if (mm.x) b0 = 255;
            if (mm.y) b1 = 255;
            if (mm.z) b2 = 255;
            if (mm.w) b3 = 255;
            w[i] = (unsigned)b0 | ((unsigned)b1 << 8) | ((unsigned)b2 << 16) | ((unsigned)b3 << 24);
        }
        uint4 u; u.x = w[0]; u.y = w[1]; u.z = w[2]; u.w = w[3];
        *(uint4*)(bins + e) = u;
    }
}

// ---------------------------------------------------------------------------
// MFMA GEMM (m97 structure), unchanged.
// ---------------------------------------------------------------------------
template <int BF16OUT>
static __device__ __forceinline__ void gemm_core(
    const unsigned short* __restrict__ A, const unsigned short* __restrict__ W,
    const float* __restrict__ bias, void* __restrict__ C,
    int Ncols, int K, float scale, int row0, int col0)
{
    __shared__ unsigned short As[128 * 32];
    __shared__ unsigned short Bs[128 * 32];

    const int t    = threadIdx.x;
    const int lane = t & 63;
    const int wave = t >> 6;
    const int wr   = wave >> 1;
    const int wc   = wave & 1;
    const int l15  = lane & 15;
    const int lhi  = lane >> 4;

    const int srow = wave * 32 + (lane >> 2);
    const int sk   = (lane & 3) * 8;
    const unsigned short* gA = A + (size_t)(row0 + srow) * K + sk;
    const unsigned short* gB = W + (size_t)(col0 + srow) * K + sk;

    floatx4 acc[4][4];
    #pragma unroll
    for (int m = 0; m < 4; ++m)
        #pragma unroll
        for (int n = 0; n < 4; ++n) acc[m][n] = (floatx4)0.f;

    for (int k0 = 0; k0 < K; k0 += 32) {
        __syncthreads();
        #pragma unroll
        for (int i = 0; i < 2; ++i) {
            __builtin_amdgcn_global_load_lds(GPTR(gA + (size_t)(i * 16) * K + k0),
                                             LPTR(&As[(wave * 32 + i * 16) * 32]), 16, 0, 0);
            __builtin_amdgcn_global_load_lds(GPTR(gB + (size_t)(i * 16) * K + k0),
                                             LPTR(&Bs[(wave * 32 + i * 16) * 32]), 16, 0, 0);
        }
        __syncthreads();

        short8 af[4], bf[4];
        #pragma unroll
        for (int m = 0; m < 4; ++m)
            af[m] = *(const short8*)&As[(wr * 64 + m * 16 + l15) * 32 + lhi * 8];
        #pragma unroll
        for (int n = 0; n < 4; ++n)
            bf[n] = *(const short8*)&Bs[(wc * 64 + n * 16 + l15) * 32 + lhi * 8];
        #pragma unroll
        for (int m = 0; m < 4; ++m)
            #pragma unroll
            for (int n = 0; n < 4; ++n)
                acc[m][n] = __builtin_amdgcn_mfma_f32_16x16x32_bf16(af[m], bf[n], acc[m][n], 0, 0, 0);
    }

    #pragma unroll
    for (int n = 0; n < 4; ++n) {
        const int col = col0 + wc * 64 + n * 16 + l15;
        const float bvv = bias[col];
        #pragma unroll
        for (int m = 0; m < 4; ++m) {
            #pragma unroll
            for (int r = 0; r < 4; ++r) {
                const int row = row0 + wr * 64 + m * 16 + lhi * 4 + r;
                const float v = (acc[m][n][r] + bvv) * scale;
                if (BF16OUT)
                    ((unsigned short*)C)[(size_t)row * Ncols + col] = f2bf(v);
                else
                    ((float*)C)[(size_t)row * Ncols + col] = v;
            }
        }
    }
}

__global__ __launch_bounds__(256) void gemm_qkv(
    const unsigned short* __restrict__ xb,
    const unsigned short* __restrict__ Wq, const unsigned short* __restrict__ Wk,
    const unsigned short* __restrict__ Wv,
    const float* __restrict__ bq, const float* __restrict__ bk,
    const float* __restrict__ bv,
    unsigned short* __restrict__ Qb, unsigned short* __restrict__ Kb,
    unsigned short* __restrict__ Vb)
{
    const int z = blockIdx.z;
    const unsigned short* W = z == 0 ? Wq : (z == 1 ? Wk : Wv);
    const float* bias       = z == 0 ? bq : (z == 1 ? bk : bv);
    unsigned short* C       = z == 0 ? Qb : (z == 1 ? Kb : Vb);
    const float scale       = z == 0 ? (0.125f * LOG2E) : 1.0f;
    gemm_core<1>(xb, W, bias, C, H_, H_, scale, blockIdx.y * 128, blockIdx.x * 128);
}

__global__ __launch_bounds__(256) void gemm_out(
    const unsigned short* __restrict__ Ab, const unsigned short* __restrict__ Wo,
    const float* __restrict__ bo, float* __restrict__ out)
{
    gemm_core<0>(Ab, Wo, bo, out, H_, H_, 1.0f, blockIdx.y * 128, blockIdx.x * 128);
}

// ---------------------------------------------------------------------------
// MFMA flash attention — R10 structure (swapped-QK^T, plain online softmax)
// + XCD-aware block swizzle: lin = qt + 16h + 128b; swz = (lin&7)*128+(lin>>3)
// gives each XCD one batch b (K/V 2MB + bins 1MB L2-resident per XCD).
// ---------------------------------------------------------------------------
__global__ __launch_bounds__(256) void attn_mfma(
    const unsigned short* __restrict__ Qg, const unsigned short* __restrict__ Kg,
    const unsigned short* __restrict__ Vg, const unsigned char* __restrict__ bins,
    const float* __restrict__ demb, const float* __restrict__ abias,
    unsigned short* __restrict__ O)
{
    // ---- XCD swizzle (bijective; 1024 = 8 * 128) ----
    const int lin = blockIdx.x + 16 * blockIdx.y + 128 * blockIdx.z;
    const int swz = (lin & 7) * 128 + (lin >> 3);
    const int qt = swz & 15;
    const int h  = (swz >> 4) & 7;
    const int b  = swz >> 7;
    const int q0 = qt * 64;
    const int t  = threadIdx.x;
    const int lane = t & 63;
    const int wave = t >> 6;
    const int l15 = lane & 15;
    const int lhi = lane >> 4;

    __shared__ unsigned short Ks[64 * 64];   // XOR-swizzled rows (linear dest)
    __shared__ unsigned short Vs[64 * 64];   // [d/16][k/4][4][16] subtiled
    __shared__ unsigned short QPs[64 * 64];  // prologue: Q; loop: per-wave P
    __shared__ unsigned char  Bs[64 * 80];   // [q][k] bins tile, stride 80

    // lane-register bias table (log2e domain); lane 63 = masked (-1.44e9)
    float dbl = -1.442695e9f;
    if (lane < 50) dbl = (demb[lane * NH_ + h] + abias[h]) * LOG2E;

    // ---- per-lane staging sources (pre-swizzled for linear LDS dest) ----
    const unsigned short* ksrc[2];
    const unsigned short* vsrc[2];
    #pragma unroll
    for (int i = 0; i < 2; ++i) {
        const int C = wave * 128 + i * 64 + lane;   // LDS 16B-chunk index
        const int kr = C >> 3, c = C & 7;
        ksrc[i] = Kg + ((size_t)(b * N_) + kr) * H_ + h * HD_ + ((c ^ (kr & 7)) * 8);
        const int vd16 = C >> 7, rem = C & 127;
        const int krhi = rem >> 3, r2 = rem & 7;
        const int vkr = krhi * 4 + (r2 >> 1), vc = r2 & 1;
        vsrc[i] = Vg + ((size_t)(b * N_) + vkr) * H_ + h * HD_ + vd16 * 16 + vc * 8;
    }
    const unsigned char* bsrc = bins + ((size_t)(b * N_) + q0 + (t >> 2)) * N_ + (t & 3) * 16;
    const int bidx = (t >> 2) * 80 + (t & 3) * 16;

    // ---- stage Q (pre-scaled by 0.125*log2e), XOR-swizzled ----
    {
        const int qr = t >> 2;
        const int d0 = (t & 3) * 16;
        const unsigned short* src = Qg + ((size_t)(b * N_ + q0 + qr)) * H_ + h * HD_ + d0;
        #pragma unroll
        for (int cc = 0; cc < 2; ++cc) {
            const uint4 v = *(const uint4*)(src + 8 * cc);
            const int idx = (qr * 64 + d0 + 8 * cc) ^ ((qr & 7) << 3);
            *(uint4*)&QPs[idx] = v;
        }
    }
    __syncthreads();

    // Q fragment (B-operand of swapped QK^T; constant over k-tiles)
    short8 aq[2];
    {
        const int qrow = (wave << 4) + l15;
        #pragma unroll
        for (int ck = 0; ck < 2; ++ck) {
            const int kb = lhi * 8 + 32 * ck;
            const int idx = (qrow * 64 + kb) ^ ((qrow & 7) << 3);
            aq[ck] = *(const short8*)&QPs[idx];
        }
    }
    __syncthreads();   // aq reads drained before QPs reused as P

    unsigned short* const Pw = &QPs[wave << 10];   // per-wave 2KB P region
    const unsigned trlane = (unsigned)(lhi << 8) + (unsigned)(l15 << 3);
    const unsigned vaddr = (unsigned)(size_t)LPTR(&Vs[0]) + trlane;

    // per-lane softmax state for q = l15 (replicated across lhi groups)
    float m = -INFINITY, lsum = 0.f;
    floatx4 o4[4];
    #pragma unroll
    for (int nd = 0; nd < 4; ++nd) o4[nd] = (floatx4)0.f;

    for (int k0 = 0; k0 < N_; k0 += 64) {
        __syncthreads();   // previous tile's reads done
        {
            const size_t koff = (size_t)k0;
            #pragma unroll
            for (int i = 0; i < 2; ++i) {
                __builtin_amdgcn_global_load_lds(GPTR(ksrc[i] + koff * H_),
                    LPTR(&Ks[(wave * 128 + i * 64) * 8]), 16, 0, 0);
                __builtin_amdgcn_global_load_lds(GPTR(vsrc[i] + koff * H_),
                    LPTR(&Vs[(wave * 128 + i * 64) * 8]), 16, 0, 0);
            }
            const uint4 brv = *(const uint4*)(bsrc + koff);
            *(uint4*)&Bs[bidx] = brv;
        }
        __syncthreads();   // staging drained

        // ---- S^T = K (Q*0.125*log2e)^T : s4[kn][r] = S[q=l15][k=kn*16+lhi*4+r]
        floatx4 s4[4];
        __builtin_amdgcn_s_setprio(1);
        #pragma unroll
        for (int kn = 0; kn < 4; ++kn) {
            const int kcol = kn * 16 + l15;
            floatx4 acc = (floatx4)0.f;
            #pragma unroll
            for (int ck = 0; ck < 2; ++ck) {
                const int kb = lhi * 8 + 32 * ck;
                const int idx = (kcol * 64 + kb) ^ ((kcol & 7) << 3);
                const short8 bk = *(const short8*)&Ks[idx];
                acc = __builtin_amdgcn_mfma_f32_16x16x32_bf16(bk, aq[ck], acc, 0, 0, 0);
            }
            s4[kn] = acc;
        }
        __builtin_amdgcn_s_setprio(0);

        // ---- + distance bias: row q=l15, contiguous k per kn ----
        #pragma unroll
        for (int kn = 0; kn < 4; ++kn) {
            const unsigned bb =
                *(const unsigned*)&Bs[((wave << 4) + l15) * 80 + kn * 16 + (lhi << 2)];
            s4[kn][0] += __shfl(dbl, (int)(bb & 255u), 64);
            s4[kn][1] += __shfl(dbl, (int)((bb >> 8) & 255u), 64);
            s4[kn][2] += __shfl(dbl, (int)((bb >> 16) & 255u), 64);
            s4[kn][3] += __shfl(dbl, (int)(bb >> 24), 64);
        }

        // ---- online softmax: lane-local over 16 regs + 2-level shfl ----
        {
            float mx = s4[0][0];
            #pragma unroll
            for (int kn = 0; kn < 4; ++kn)
                #pragma unroll
                for (int r = 0; r < 4; ++r) mx = fmaxf(mx, s4[kn][r]);
            mx = fmaxf(mx, __shfl_xor(mx, 16, 64));
            mx = fmaxf(mx, __shfl_xor(mx, 32, 64));
            const float mnew = fmaxf(m, mx);
            float ts = 0.f;
            #pragma unroll
            for (int kn = 0; kn < 4; ++kn)
                #pragma unroll
                for (int r = 0; r < 4; ++r) {
                    const float p = EXP2(s4[kn][r] - mnew);
                    s4[kn][r] = p;
                    ts += p;
                }
            ts += __shfl_xor(ts, 16, 64);
            ts += __shfl_xor(ts, 32, 64);
            const float alpha = EXP2(m - mnew);
            lsum = lsum * alpha + ts;
            m = mnew;
            // broadcast alpha to O rows (q = lhi*4+r lives at lane l15=q)
            #pragma unroll
            for (int r = 0; r < 4; ++r) {
                const float ar = __shfl(alpha, lhi * 4 + r, 64);
                #pragma unroll
                for (int nd = 0; nd < 4; ++nd) o4[nd][r] *= ar;
            }
        }

        // ---- P[q=l15][k] -> LDS: 4 b64 writes at contiguous k ----
        #pragma unroll
        for (int kn = 0; kn < 4; ++kn) {
            short4_t pk;
            pk[0] = (short)f2bf(s4[kn][0]);
            pk[1] = (short)f2bf(s4[kn][1]);
            pk[2] = (short)f2bf(s4[kn][2]);
            pk[3] = (short)f2bf(s4[kn][3]);
            const int idx = (l15 * 64 + kn * 16 + (lhi << 2)) ^ ((l15 & 7) << 3);
            *(short4_t*)&Pw[idx] = pk;
        }

        // ---- PV: A = 2 direct b128 P reads; B = 16 V tr-reads ----
        short8 ap[2];
        #pragma unroll
        for (int ck = 0; ck < 2; ++ck) {
            const int idx = (l15 * 64 + ck * 32 + lhi * 8) ^ ((l15 & 7) << 3);
            ap[ck] = *(const short8*)&Pw[idx];
        }
        short4_t v0l[4], v0h[4], v1l[4], v1h[4];
        TRB16(v0l[0], vaddr, "0");    TRB16(v0h[0], vaddr, "128");
        TRB16(v0l[1], vaddr, "2048"); TRB16(v0h[1], vaddr, "2176");
        TRB16(v0l[2], vaddr, "4096"); TRB16(v0h[2], vaddr, "4224");
        TRB16(v0l[3], vaddr, "6144"); TRB16(v0h[3], vaddr, "6272");
        TRB16(v1l[0], vaddr, "1024"); TRB16(v1h[0], vaddr, "1152");
        TRB16(v1l[1], vaddr, "3072"); TRB16(v1h[1], vaddr, "3200");
        TRB16(v1l[2], vaddr, "5120"); TRB16(v1h[2], vaddr, "5248");
        TRB16(v1l[3], vaddr, "7168"); TRB16(v1h[3], vaddr, "7296");
        asm volatile("s_waitcnt lgkmcnt(0)" ::: "memory");
        __builtin_amdgcn_sched_barrier(0);

        __builtin_amdgcn_s_setprio(1);
        #pragma unroll
        for (int nd = 0; nd < 4; ++nd) {
            const short8 bv0 = __builtin_shufflevector(v0l[nd], v0h[nd], 0, 1, 2, 3, 4, 5, 6, 7);
            o4[nd] = __builtin_amdgcn_mfma_f32_16x16x32_bf16(ap[0], bv0, o4[nd], 0, 0, 0);
            const short8 bv1 = __builtin_shufflevector(v1l[nd], v1h[nd], 0, 1, 2, 3, 4, 5, 6, 7);
            o4[nd] = __builtin_amdgcn_mfma_f32_16x16x32_bf16(ap[1], bv1, o4[nd], 0, 0, 0);
        }
        __builtin_amdgcn_s_setprio(0);
    }

    // ---- epilogue: pull lsum for q=lhi*4+r, normalize, write ----
    float inv[4];
    #pragma unroll
    for (int r = 0; r < 4; ++r) inv[r] = 1.f / __shfl(lsum, lhi * 4 + r, 64);
    #pragma unroll
    for (int nd = 0; nd < 4; ++nd) {
        const int d = nd * 16 + l15;
        #pragma unroll
        for (int r = 0; r < 4; ++r) {
            const int q = q0 + (wave << 4) + lhi * 4 + r;
            O[((size_t)(b * N_ + q)) * H_ + h * HD_ + d] = f2bf(o4[nd][r] * inv[r]);
        }
    }
}

// ---------------------------------------------------------------------------
extern "C" void kernel_launch(void* const* d_in, const int* in_sizes, int n_in,
                              void* d_out, int out_size, void* d_ws, size_t ws_size,
                              hipStream_t stream)
{
    const float* x    = (const float*)d_in[0];
    const float* dist = (const float*)d_in[1];
    const int*   mask = (const int*)d_in[2];
    const float* Wq   = (const float*)d_in[3];
    const float* bq   = (const float*)d_in[4];
    const float* Wk   = (const float*)d_in[5];
    const float* bk   = (const float*)d_in[6];
    const float* Wv   = (const float*)d_in[7];
    const float* bv   = (const float*)d_in[8];
    const float* Wo   = (const float*)d_in[9];
    const float* bo   = (const float*)d_in[10];
    const float* demb = (const float*)d_in[11];
    const float* ab   = (const float*)d_in[12];
    float* out = (float*)d_out;

    const size_t mat = (size_t)B_ * N_ * H_;         // 4,194,304
    const size_t wsz = (size_t)H_ * H_;              //   262,144

    unsigned short* blob = (unsigned short*)d_ws;
    unsigned short* xb  = blob;
    unsigned short* Wqb = blob + mat;
    unsigned short* Wkb = Wqb + wsz;
    unsigned short* Wvb = Wkb + wsz;
    unsigned short* Wob = Wvb + wsz;
    unsigned short* Qb  = Wob + wsz;
    unsigned short* Kb  = Qb + mat;
    unsigned short* Vb  = Kb + mat;
    unsigned short* Ab  = Vb + mat;
    unsigned char*  binsb = (unsigned char*)(Ab + mat);

    const dim3 blk(256);

    hipLaunchKernelGGL(prep_kernel, dim3(3328), blk, 0, stream,
                       x, Wq, Wk, Wv, Wo, blob, dist, mask, binsb);

    const dim3 qgrid(H_ / 128, (B_ * N_) / 128, 3);
    hipLaunchKernelGGL(gemm_qkv, qgrid, blk, 0, stream,
                       xb, Wqb, Wkb, Wvb, bq, bk, bv, Qb, Kb, Vb);

    const dim3 agrid(N_ / 64, NH_, B_);
    hipLaunchKernelGGL(attn_mfma, agrid, blk, 0, stream,
                       Qb, Kb, Vb, binsb, demb, ab, Ab);

    const dim3 ogrid(H_ / 128, (B_ * N_) / 128, 1);
    hipLaunchKernelGGL(gemm_out, ogrid, blk, 0, stream, Ab, Wob, bo, out);
}

// Round 14
// 103.150 us; speedup vs baseline: 1.3600x; 1.0373x over previous
//
#include <hip/hip_runtime.h>
#include <hip/hip_bf16.h>
#include <math.h>

#define B_  8
#define N_  1024
#define H_  512
#define NH_ 8
#define HD_ 64

typedef __attribute__((ext_vector_type(8))) short short8;
typedef __attribute__((ext_vector_type(4))) short short4_t;
typedef __attribute__((ext_vector_type(4))) float floatx4;

#define GPTR(p) ((const __attribute__((address_space(1))) void*)(p))
#define LPTR(p) ((__attribute__((address_space(3))) void*)(p))

// ds_read_b64_tr_b16: lane l elem j <- lds[region + j*16 + (l&15)] (bf16 elems)
#define TRB16(dst, addr, IMM) \
    asm volatile("ds_read_b64_tr_b16 %0, %1 offset:" IMM \
                 : "=v"(dst) : "v"(addr) : "memory")

#define EXP2(x) exp2f(x)
#define LOG2E 1.44269504088896f

static __device__ __forceinline__ unsigned short f2bf(float f) {
    __hip_bfloat16 h = __float2bfloat16(f);
    unsigned short u;
    __builtin_memcpy(&u, &h, 2);
    return u;
}

// ---------------------------------------------------------------------------
// prep: [blocks 0,1280): fp32->bf16 blob [xb | Wq | Wk | Wv | Wo]
//       [blocks 1280,3328): bins[b][q][k] = mask ? 255 : clip(d*10,0,49)
// ---------------------------------------------------------------------------
__global__ __launch_bounds__(256) void prep_kernel(
    const float* __restrict__ x,  const float* __restrict__ wq,
    const float* __restrict__ wk, const float* __restrict__ wv,
    const float* __restrict__ wo, unsigned short* __restrict__ dst,
    const float* __restrict__ dist, const int* __restrict__ mask,
    unsigned char* __restrict__ bins)
{
    const int bid = blockIdx.x;
    if (bid < 1280) {
        const int n4 = (4194304 + 4 * 262144) / 4;
        int i = bid * 256 + threadIdx.x;
        for (; i < n4; i += 1280 * 256) {
            const int e = i * 4;
            const float* src;
            if (e < 4194304) {
                src = x + e;
            } else {
                const int rel = e - 4194304;
                const int w = rel >> 18;
                const int off = rel & 262143;
                src = (w == 0 ? wq : w == 1 ? wk : w == 2 ? wv : wo) + off;
            }
            const float4 v = *(const float4*)src;
            ushort4 r;
            r.x = f2bf(v.x); r.y = f2bf(v.y); r.z = f2bf(v.z); r.w = f2bf(v.w);
            *(ushort4*)(dst + e) = r;
        }
    } else {
        const int gid = (bid - 1280) * 256 + threadIdx.x;   // 524288 total
        const size_t e = (size_t)gid * 16;
        const int b = gid >> 16;
        const int k = (gid & 63) * 16;
        const float* dsrc = dist + e;
        const int*   msrc = mask + b * N_ + k;
        unsigned w[4];
        #pragma unroll
        for (int i = 0; i < 4; ++i) {
            const float4 v = *(const float4*)(dsrc + 4 * i);
            const int4  mm = *(const int4*)(msrc + 4 * i);
            int b0 = (int)(v.x * 10.f); b0 = b0 < 0 ? 0 : (b0 > 49 ? 49 : b0);
            int b1 = (int)(v.y * 10.f); b1 = b1 < 0 ? 0 : (b1 > 49 ? 49 : b1);
            int b2 = (int)(v.z * 10.f); b2 = b2 < 0 ? 0 : (b2 > 49 ? 49 : b2);
            int b3 = (int)(v.w * 10.f); b3 = b3 < 0 ? 0 : (b3 > 49 ? 49 : b3);
            if (mm.x) b0 = 255;
            if (mm.y) b1 = 255;
            if (mm.z) b2 = 255;
            if (mm.w) b3 = 255;
            w[i] = (unsigned)b0 | ((unsigned)b1 << 8) | ((unsigned)b2 << 16) | ((unsigned)b3 << 24);
        }
        uint4 u; u.x = w[0]; u.y = w[1]; u.z = w[2]; u.w = w[3];
        *(uint4*)(bins + e) = u;
    }
}

// ---------------------------------------------------------------------------
// MFMA GEMM (m97 structure), unchanged.
// ---------------------------------------------------------------------------
template <int BF16OUT>
static __device__ __forceinline__ void gemm_core(
    const unsigned short* __restrict__ A, const unsigned short* __restrict__ W,
    const float* __restrict__ bias, void* __restrict__ C,
    int Ncols, int K, float scale, int row0, int col0)
{
    __shared__ unsigned short As[128 * 32];
    __shared__ unsigned short Bs[128 * 32];

    const int t    = threadIdx.x;
    const int lane = t & 63;
    const int wave = t >> 6;
    const int wr   = wave >> 1;
    const int wc   = wave & 1;
    const int l15  = lane & 15;
    const int lhi  = lane >> 4;

    const int srow = wave * 32 + (lane >> 2);
    const int sk   = (lane & 3) * 8;
    const unsigned short* gA = A + (size_t)(row0 + srow) * K + sk;
    const unsigned short* gB = W + (size_t)(col0 + srow) * K + sk;

    floatx4 acc[4][4];
    #pragma unroll
    for (int m = 0; m < 4; ++m)
        #pragma unroll
        for (int n = 0; n < 4; ++n) acc[m][n] = (floatx4)0.f;

    for (int k0 = 0; k0 < K; k0 += 32) {
        __syncthreads();
        #pragma unroll
        for (int i = 0; i < 2; ++i) {
            __builtin_amdgcn_global_load_lds(GPTR(gA + (size_t)(i * 16) * K + k0),
                                             LPTR(&As[(wave * 32 + i * 16) * 32]), 16, 0, 0);
            __builtin_amdgcn_global_load_lds(GPTR(gB + (size_t)(i * 16) * K + k0),
                                             LPTR(&Bs[(wave * 32 + i * 16) * 32]), 16, 0, 0);
        }
        __syncthreads();

        short8 af[4], bf[4];
        #pragma unroll
        for (int m = 0; m < 4; ++m)
            af[m] = *(const short8*)&As[(wr * 64 + m * 16 + l15) * 32 + lhi * 8];
        #pragma unroll
        for (int n = 0; n < 4; ++n)
            bf[n] = *(const short8*)&Bs[(wc * 64 + n * 16 + l15) * 32 + lhi * 8];
        #pragma unroll
        for (int m = 0; m < 4; ++m)
            #pragma unroll
            for (int n = 0; n < 4; ++n)
                acc[m][n] = __builtin_amdgcn_mfma_f32_16x16x32_bf16(af[m], bf[n], acc[m][n], 0, 0, 0);
    }

    #pragma unroll
    for (int n = 0; n < 4; ++n) {
        const int col = col0 + wc * 64 + n * 16 + l15;
        const float bvv = bias[col];
        #pragma unroll
        for (int m = 0; m < 4; ++m) {
            #pragma unroll
            for (int r = 0; r < 4; ++r) {
                const int row = row0 + wr * 64 + m * 16 + lhi * 4 + r;
                const float v = (acc[m][n][r] + bvv) * scale;
                if (BF16OUT)
                    ((unsigned short*)C)[(size_t)row * Ncols + col] = f2bf(v);
                else
                    ((float*)C)[(size_t)row * Ncols + col] = v;
            }
        }
    }
}

__global__ __launch_bounds__(256) void gemm_qkv(
    const unsigned short* __restrict__ xb,
    const unsigned short* __restrict__ Wq, const unsigned short* __restrict__ Wk,
    const unsigned short* __restrict__ Wv,
    const float* __restrict__ bq, const float* __restrict__ bk,
    const float* __restrict__ bv,
    unsigned short* __restrict__ Qb, unsigned short* __restrict__ Kb,
    unsigned short* __restrict__ Vb)
{
    const int z = blockIdx.z;
    const unsigned short* W = z == 0 ? Wq : (z == 1 ? Wk : Wv);
    const float* bias       = z == 0 ? bq : (z == 1 ? bk : bv);
    unsigned short* C       = z == 0 ? Qb : (z == 1 ? Kb : Vb);
    const float scale       = z == 0 ? (0.125f * LOG2E) : 1.0f;
    gemm_core<1>(xb, W, bias, C, H_, H_, scale, blockIdx.y * 128, blockIdx.x * 128);
}

__global__ __launch_bounds__(256) void gemm_out(
    const unsigned short* __restrict__ Ab, const unsigned short* __restrict__ Wo,
    const float* __restrict__ bo, float* __restrict__ out)
{
    gemm_core<0>(Ab, Wo, bo, out, H_, H_, 1.0f, blockIdx.y * 128, blockIdx.x * 128);
}

// ---------------------------------------------------------------------------
// MFMA flash attention — R13 structure widened to 8 waves / 128-q blocks.
// 512 blocks = exactly 2/CU, 16 waves/CU (4/SIMD, was ~2.5). Each of the 8
// waves owns 16 q rows; all share one 64-k K/V tile (staging cost per wave
// halves). Per-thread dataflow identical to R13 (validated R10 structure).
// ---------------------------------------------------------------------------
__global__ __launch_bounds__(512) void attn_mfma(
    const unsigned short* __restrict__ Qg, const unsigned short* __restrict__ Kg,
    const unsigned short* __restrict__ Vg, const unsigned char* __restrict__ bins,
    const float* __restrict__ demb, const float* __restrict__ abias,
    unsigned short* __restrict__ O)
{
    // ---- XCD swizzle (bijective; 512 = 8 XCD * 64) ----
    const int lin = blockIdx.x + 8 * blockIdx.y + 64 * blockIdx.z;
    const int swz = (lin & 7) * 64 + (lin >> 3);
    const int qt = swz & 7;          // 0..7 (128-q tiles)
    const int h  = (swz >> 3) & 7;
    const int b  = swz >> 6;
    const int q0 = qt * 128;
    const int t  = threadIdx.x;      // 0..511
    const int lane = t & 63;
    const int wave = t >> 6;         // 0..7
    const int l15 = lane & 15;
    const int lhi = lane >> 4;

    __shared__ unsigned short Ks[64 * 64];    // 8KB, XOR-swizzled rows
    __shared__ unsigned short Vs[64 * 64];    // 8KB, subtiled
    __shared__ unsigned short QPs[128 * 64];  // 16KB: Q prologue, then 8x2KB P
    __shared__ unsigned char  Bs[128 * 80];   // 10KB: [q][k] bins tile

    // lane-register bias table (log2e domain); lane 63 = masked (-1.44e9)
    float dbl = -1.442695e9f;
    if (lane < 50) dbl = (demb[lane * NH_ + h] + abias[h]) * LOG2E;

    // ---- per-lane staging sources (pre-swizzled for linear LDS dest) ----
    // wave w stages chunks C = w*64 + lane (one 16B chunk each for K and V)
    const int C = wave * 64 + lane;
    const int kr = C >> 3, kc = C & 7;
    const unsigned short* ksrc =
        Kg + ((size_t)(b * N_) + kr) * H_ + h * HD_ + ((kc ^ (kr & 7)) * 8);
    const int vd16 = C >> 7, vrem = C & 127;
    const int vkrhi = vrem >> 3, vr2 = vrem & 7;
    const int vkr = vkrhi * 4 + (vr2 >> 1), vcc = vr2 & 1;
    const unsigned short* vsrc =
        Vg + ((size_t)(b * N_) + vkr) * H_ + h * HD_ + vd16 * 16 + vcc * 8;
    const unsigned char* bsrc = bins + ((size_t)(b * N_) + q0 + (t >> 2)) * N_ + (t & 3) * 16;
    const int bidx = (t >> 2) * 80 + (t & 3) * 16;

    // ---- stage Q (pre-scaled by 0.125*log2e), XOR-swizzled: 128 rows ----
    {
        const int qr = t >> 2;           // 0..127
        const int d0 = (t & 3) * 16;
        const unsigned short* src = Qg + ((size_t)(b * N_ + q0 + qr)) * H_ + h * HD_ + d0;
        #pragma unroll
        for (int cc = 0; cc < 2; ++cc) {
            const uint4 v = *(const uint4*)(src + 8 * cc);
            const int idx = (qr * 64 + d0 + 8 * cc) ^ ((qr & 7) << 3);
            *(uint4*)&QPs[idx] = v;
        }
    }
    __syncthreads();

    // Q fragment (B-operand of swapped QK^T; wave owns rows wave*16..+15)
    short8 aq[2];
    {
        const int qrow = (wave << 4) + l15;
        #pragma unroll
        for (int ck = 0; ck < 2; ++ck) {
            const int kb = lhi * 8 + 32 * ck;
            const int idx = (qrow * 64 + kb) ^ ((qrow & 7) << 3);
            aq[ck] = *(const short8*)&QPs[idx];
        }
    }
    __syncthreads();   // aq reads drained before QPs reused as P

    unsigned short* const Pw = &QPs[wave << 10];   // per-wave 2KB P region
    const unsigned trlane = (unsigned)(lhi << 8) + (unsigned)(l15 << 3);
    const unsigned vaddr = (unsigned)(size_t)LPTR(&Vs[0]) + trlane;

    // per-lane softmax state for q = l15 (within this wave's 16-q group)
    float m = -INFINITY, lsum = 0.f;
    floatx4 o4[4];
    #pragma unroll
    for (int nd = 0; nd < 4; ++nd) o4[nd] = (floatx4)0.f;

    for (int k0 = 0; k0 < N_; k0 += 64) {
        __syncthreads();   // previous tile's reads done
        {
            const size_t koff = (size_t)k0;
            __builtin_amdgcn_global_load_lds(GPTR(ksrc + koff * H_),
                LPTR(&Ks[(wave * 64) * 8]), 16, 0, 0);
            __builtin_amdgcn_global_load_lds(GPTR(vsrc + koff * H_),
                LPTR(&Vs[(wave * 64) * 8]), 16, 0, 0);
            const uint4 brv = *(const uint4*)(bsrc + koff);
            *(uint4*)&Bs[bidx] = brv;
        }
        __syncthreads();   // staging drained

        // ---- S^T = K (Q*0.125*log2e)^T : s4[kn][r] = S[q=l15][k=kn*16+lhi*4+r]
        floatx4 s4[4];
        __builtin_amdgcn_s_setprio(1);
        #pragma unroll
        for (int kn = 0; kn < 4; ++kn) {
            const int kcol = kn * 16 + l15;
            floatx4 acc = (floatx4)0.f;
            #pragma unroll
            for (int ck = 0; ck < 2; ++ck) {
                const int kb = lhi * 8 + 32 * ck;
                const int idx = (kcol * 64 + kb) ^ ((kcol & 7) << 3);
                const short8 bk = *(const short8*)&Ks[idx];
                acc = __builtin_amdgcn_mfma_f32_16x16x32_bf16(bk, aq[ck], acc, 0, 0, 0);
            }
            s4[kn] = acc;
        }
        __builtin_amdgcn_s_setprio(0);

        // ---- + distance bias: row q=l15 (wave group), contiguous k per kn ----
        #pragma unroll
        for (int kn = 0; kn < 4; ++kn) {
            const unsigned bb =
                *(const unsigned*)&Bs[((wave << 4) + l15) * 80 + kn * 16 + (lhi << 2)];
            s4[kn][0] += __shfl(dbl, (int)(bb & 255u), 64);
            s4[kn][1] += __shfl(dbl, (int)((bb >> 8) & 255u), 64);
            s4[kn][2] += __shfl(dbl, (int)((bb >> 16) & 255u), 64);
            s4[kn][3] += __shfl(dbl, (int)(bb >> 24), 64);
        }

        // ---- online softmax: lane-local over 16 regs + 2-level shfl ----
        {
            float mx = s4[0][0];
            #pragma unroll
            for (int kn = 0; kn < 4; ++kn)
                #pragma unroll
                for (int r = 0; r < 4; ++r) mx = fmaxf(mx, s4[kn][r]);
            mx = fmaxf(mx, __shfl_xor(mx, 16, 64));
            mx = fmaxf(mx, __shfl_xor(mx, 32, 64));
            const float mnew = fmaxf(m, mx);
            float ts = 0.f;
            #pragma unroll
            for (int kn = 0; kn < 4; ++kn)
                #pragma unroll
                for (int r = 0; r < 4; ++r) {
                    const float p = EXP2(s4[kn][r] - mnew);
                    s4[kn][r] = p;
                    ts += p;
                }
            ts += __shfl_xor(ts, 16, 64);
            ts += __shfl_xor(ts, 32, 64);
            const float alpha = EXP2(m - mnew);
            lsum = lsum * alpha + ts;
            m = mnew;
            // broadcast alpha to O rows (q = lhi*4+r lives at lane l15=q)
            #pragma unroll
            for (int r = 0; r < 4; ++r) {
                const float ar = __shfl(alpha, lhi * 4 + r, 64);
                #pragma unroll
                for (int nd = 0; nd < 4; ++nd) o4[nd][r] *= ar;
            }
        }

        // ---- P[q=l15][k] -> LDS: 4 b64 writes at contiguous k ----
        #pragma unroll
        for (int kn = 0; kn < 4; ++kn) {
            short4_t pk;
            pk[0] = (short)f2bf(s4[kn][0]);
            pk[1] = (short)f2bf(s4[kn][1]);
            pk[2] = (short)f2bf(s4[kn][2]);
            pk[3] = (short)f2bf(s4[kn][3]);
            const int idx = (l15 * 64 + kn * 16 + (lhi << 2)) ^ ((l15 & 7) << 3);
            *(short4_t*)&Pw[idx] = pk;
        }

        // ---- PV: A = 2 direct b128 P reads; B = 16 V tr-reads ----
        short8 ap[2];
        #pragma unroll
        for (int ck = 0; ck < 2; ++ck) {
            const int idx = (l15 * 64 + ck * 32 + lhi * 8) ^ ((l15 & 7) << 3);
            ap[ck] = *(const short8*)&Pw[idx];
        }
        short4_t v0l[4], v0h[4], v1l[4], v1h[4];
        TRB16(v0l[0], vaddr, "0");    TRB16(v0h[0], vaddr, "128");
        TRB16(v0l[1], vaddr, "2048"); TRB16(v0h[1], vaddr, "2176");
        TRB16(v0l[2], vaddr, "4096"); TRB16(v0h[2], vaddr, "4224");
        TRB16(v0l[3], vaddr, "6144"); TRB16(v0h[3], vaddr, "6272");
        TRB16(v1l[0], vaddr, "1024"); TRB16(v1h[0], vaddr, "1152");
        TRB16(v1l[1], vaddr, "3072"); TRB16(v1h[1], vaddr, "3200");
        TRB16(v1l[2], vaddr, "5120"); TRB16(v1h[2], vaddr, "5248");
        TRB16(v1l[3], vaddr, "7168"); TRB16(v1h[3], vaddr, "7296");
        asm volatile("s_waitcnt lgkmcnt(0)" ::: "memory");
        __builtin_amdgcn_sched_barrier(0);

        __builtin_amdgcn_s_setprio(1);
        #pragma unroll
        for (int nd = 0; nd < 4; ++nd) {
            const short8 bv0 = __builtin_shufflevector(v0l[nd], v0h[nd], 0, 1, 2, 3, 4, 5, 6, 7);
            o4[nd] = __builtin_amdgcn_mfma_f32_16x16x32_bf16(ap[0], bv0, o4[nd], 0, 0, 0);
            const short8 bv1 = __builtin_shufflevector(v1l[nd], v1h[nd], 0, 1, 2, 3, 4, 5, 6, 7);
            o4[nd] = __builtin_amdgcn_mfma_f32_16x16x32_bf16(ap[1], bv1, o4[nd], 0, 0, 0);
        }
        __builtin_amdgcn_s_setprio(0);
    }

    // ---- epilogue: pull lsum for q=lhi*4+r, normalize, write ----
    float inv[4];
    #pragma unroll
    for (int r = 0; r < 4; ++r) inv[r] = 1.f / __shfl(lsum, lhi * 4 + r, 64);
    #pragma unroll
    for (int nd = 0; nd < 4; ++nd) {
        const int d = nd * 16 + l15;
        #pragma unroll
        for (int r = 0; r < 4; ++r) {
            const int q = q0 + (wave << 4) + lhi * 4 + r;
            O[((size_t)(b * N_ + q)) * H_ + h * HD_ + d] = f2bf(o4[nd][r] * inv[r]);
        }
    }
}

// ---------------------------------------------------------------------------
extern "C" void kernel_launch(void* const* d_in, const int* in_sizes, int n_in,
                              void* d_out, int out_size, void* d_ws, size_t ws_size,
                              hipStream_t stream)
{
    const float* x    = (const float*)d_in[0];
    const float* dist = (const float*)d_in[1];
    const int*   mask = (const int*)d_in[2];
    const float* Wq   = (const float*)d_in[3];
    const float* bq   = (const float*)d_in[4];
    const float* Wk   = (const float*)d_in[5];
    const float* bk   = (const float*)d_in[6];
    const float* Wv   = (const float*)d_in[7];
    const float* bv   = (const float*)d_in[8];
    const float* Wo   = (const float*)d_in[9];
    const float* bo   = (const float*)d_in[10];
    const float* demb = (const float*)d_in[11];
    const float* ab   = (const float*)d_in[12];
    float* out = (float*)d_out;

    const size_t mat = (size_t)B_ * N_ * H_;         // 4,194,304
    const size_t wsz = (size_t)H_ * H_;              //   262,144

    unsigned short* blob = (unsigned short*)d_ws;
    unsigned short* xb  = blob;
    unsigned short* Wqb = blob + mat;
    unsigned short* Wkb = Wqb + wsz;
    unsigned short* Wvb = Wkb + wsz;
    unsigned short* Wob = Wvb + wsz;
    unsigned short* Qb  = Wob + wsz;
    unsigned short* Kb  = Qb + mat;
    unsigned short* Vb  = Kb + mat;
    unsigned short* Ab  = Vb + mat;
    unsigned char*  binsb = (unsigned char*)(Ab + mat);

    const dim3 blk(256);

    hipLaunchKernelGGL(prep_kernel, dim3(3328), blk, 0, stream,
                       x, Wq, Wk, Wv, Wo, blob, dist, mask, binsb);

    const dim3 qgrid(H_ / 128, (B_ * N_) / 128, 3);
    hipLaunchKernelGGL(gemm_qkv, qgrid, blk, 0, stream,
                       xb, Wqb, Wkb, Wvb, bq, bk, bv, Qb, Kb, Vb);

    const dim3 agrid(N_ / 128, NH_, B_);             // (8, 8, 8) = 512 blocks
    hipLaunchKernelGGL(attn_mfma, agrid, dim3(512), 0, stream,
                       Qb, Kb, Vb, binsb, demb, ab, Ab);

    const dim3 ogrid(H_ / 128, (B_ * N_) / 128, 1);
    hipLaunchKernelGGL(gemm_out, ogrid, blk, 0, stream, Ab, Wob, bo, out);
}

// Round 15
// 101.970 us; speedup vs baseline: 1.3758x; 1.0116x over previous
//
#include <hip/hip_runtime.h>
#include <hip/hip_bf16.h>
#include <math.h>

#define B_  8
#define N_  1024
#define H_  512
#define NH_ 8
#define HD_ 64

typedef __attribute__((ext_vector_type(8))) short short8;
typedef __attribute__((ext_vector_type(4))) short short4_t;
typedef __attribute__((ext_vector_type(4))) float floatx4;

#define GPTR(p) ((const __attribute__((address_space(1))) void*)(p))
#define LPTR(p) ((__attribute__((address_space(3))) void*)(p))

// ds_read_b64_tr_b16: lane l elem j <- lds[region + j*16 + (l&15)] (bf16 elems)
#define TRB16(dst, addr, IMM) \
    asm volatile("ds_read_b64_tr_b16 %0, %1 offset:" IMM \
                 : "=v"(dst) : "v"(addr) : "memory")

#define EXP2(x) exp2f(x)
#define LOG2E 1.44269504088896f

static __device__ __forceinline__ unsigned short f2bf(float f) {
    __hip_bfloat16 h = __float2bfloat16(f);
    unsigned short u;
    __builtin_memcpy(&u, &h, 2);
    return u;
}

// ---------------------------------------------------------------------------
// prep: [blocks 0,1280): fp32->bf16 blob [xb | Wq | Wk | Wv | Wo]
//       [blocks 1280,3328): bins[b][q][k] = mask ? 255 : clip(d*10,0,49)
// ---------------------------------------------------------------------------
__global__ __launch_bounds__(256) void prep_kernel(
    const float* __restrict__ x,  const float* __restrict__ wq,
    const float* __restrict__ wk, const float* __restrict__ wv,
    const float* __restrict__ wo, unsigned short* __restrict__ dst,
    const float* __restrict__ dist, const int* __restrict__ mask,
    unsigned char* __restrict__ bins)
{
    const int bid = blockIdx.x;
    if (bid < 1280) {
        const int n4 = (4194304 + 4 * 262144) / 4;
        int i = bid * 256 + threadIdx.x;
        for (; i < n4; i += 1280 * 256) {
            const int e = i * 4;
            const float* src;
            if (e < 4194304) {
                src = x + e;
            } else {
                const int rel = e - 4194304;
                const int w = rel >> 18;
                const int off = rel & 262143;
                src = (w == 0 ? wq : w == 1 ? wk : w == 2 ? wv : wo) + off;
            }
            const float4 v = *(const float4*)src;
            ushort4 r;
            r.x = f2bf(v.x); r.y = f2bf(v.y); r.z = f2bf(v.z); r.w = f2bf(v.w);
            *(ushort4*)(dst + e) = r;
        }
    } else {
        const int gid = (bid - 1280) * 256 + threadIdx.x;   // 524288 total
        const size_t e = (size_t)gid * 16;
        const int b = gid >> 16;
        const int k = (gid & 63) * 16;
        const float* dsrc = dist + e;
        const int*   msrc = mask + b * N_ + k;
        unsigned w[4];
        #pragma unroll
        for (int i = 0; i < 4; ++i) {
            const float4 v = *(const float4*)(dsrc + 4 * i);
            const int4  mm = *(const int4*)(msrc + 4 * i);
            int b0 = (int)(v.x * 10.f); b0 = b0 < 0 ? 0 : (b0 > 49 ? 49 : b0);
            int b1 = (int)(v.y * 10.f); b1 = b1 < 0 ? 0 : (b1 > 49 ? 49 : b1);
            int b2 = (int)(v.z * 10.f); b2 = b2 < 0 ? 0 : (b2 > 49 ? 49 : b2);
            int b3 = (int)(v.w * 10.f); b3 = b3 < 0 ? 0 : (b3 > 49 ? 49 : b3);
            if (mm.x) b0 = 255;
            if (mm.y) b1 = 255;
            if (mm.z) b2 = 255;
            if (mm.w) b3 = 255;
            w[i] = (unsigned)b0 | ((unsigned)b1 << 8) | ((unsigned)b2 << 16) | ((unsigned)b3 << 24);
        }
        uint4 u; u.x = w[0]; u.y = w[1]; u.z = w[2]; u.w = w[3];
        *(uint4*)(bins + e) = u;
    }
}

// ---------------------------------------------------------------------------
// MFMA GEMM (m97 structure), unchanged.
// ---------------------------------------------------------------------------
template <int BF16OUT>
static __device__ __forceinline__ void gemm_core(
    const unsigned short* __restrict__ A, const unsigned short* __restrict__ W,
    const float* __restrict__ bias, void* __restrict__ C,
    int Ncols, int K, float scale, int row0, int col0)
{
    __shared__ unsigned short As[128 * 32];
    __shared__ unsigned short Bs[128 * 32];

    const int t    = threadIdx.x;
    const int lane = t & 63;
    const int wave = t >> 6;
    const int wr   = wave >> 1;
    const int wc   = wave & 1;
    const int l15  = lane & 15;
    const int lhi  = lane >> 4;

    const int srow = wave * 32 + (lane >> 2);
    const int sk   = (lane & 3) * 8;
    const unsigned short* gA = A + (size_t)(row0 + srow) * K + sk;
    const unsigned short* gB = W + (size_t)(col0 + srow) * K + sk;

    floatx4 acc[4][4];
    #pragma unroll
    for (int m = 0; m < 4; ++m)
        #pragma unroll
        for (int n = 0; n < 4; ++n) acc[m][n] = (floatx4)0.f;

    for (int k0 = 0; k0 < K; k0 += 32) {
        __syncthreads();
        #pragma unroll
        for (int i = 0; i < 2; ++i) {
            __builtin_amdgcn_global_load_lds(GPTR(gA + (size_t)(i * 16) * K + k0),
                                             LPTR(&As[(wave * 32 + i * 16) * 32]), 16, 0, 0);
            __builtin_amdgcn_global_load_lds(GPTR(gB + (size_t)(i * 16) * K + k0),
                                             LPTR(&Bs[(wave * 32 + i * 16) * 32]), 16, 0, 0);
        }
        __syncthreads();

        short8 af[4], bf[4];
        #pragma unroll
        for (int m = 0; m < 4; ++m)
            af[m] = *(const short8*)&As[(wr * 64 + m * 16 + l15) * 32 + lhi * 8];
        #pragma unroll
        for (int n = 0; n < 4; ++n)
            bf[n] = *(const short8*)&Bs[(wc * 64 + n * 16 + l15) * 32 + lhi * 8];
        #pragma unroll
        for (int m = 0; m < 4; ++m)
            #pragma unroll
            for (int n = 0; n < 4; ++n)
                acc[m][n] = __builtin_amdgcn_mfma_f32_16x16x32_bf16(af[m], bf[n], acc[m][n], 0, 0, 0);
    }

    #pragma unroll
    for (int n = 0; n < 4; ++n) {
        const int col = col0 + wc * 64 + n * 16 + l15;
        const float bvv = bias[col];
        #pragma unroll
        for (int m = 0; m < 4; ++m) {
            #pragma unroll
            for (int r = 0; r < 4; ++r) {
                const int row = row0 + wr * 64 + m * 16 + lhi * 4 + r;
                const float v = (acc[m][n][r] + bvv) * scale;
                if (BF16OUT)
                    ((unsigned short*)C)[(size_t)row * Ncols + col] = f2bf(v);
                else
                    ((float*)C)[(size_t)row * Ncols + col] = v;
            }
        }
    }
}

__global__ __launch_bounds__(256) void gemm_qkv(
    const unsigned short* __restrict__ xb,
    const unsigned short* __restrict__ Wq, const unsigned short* __restrict__ Wk,
    const unsigned short* __restrict__ Wv,
    const float* __restrict__ bq, const float* __restrict__ bk,
    const float* __restrict__ bv,
    unsigned short* __restrict__ Qb, unsigned short* __restrict__ Kb,
    unsigned short* __restrict__ Vb)
{
    const int z = blockIdx.z;
    const unsigned short* W = z == 0 ? Wq : (z == 1 ? Wk : Wv);
    const float* bias       = z == 0 ? bq : (z == 1 ? bk : bv);
    unsigned short* C       = z == 0 ? Qb : (z == 1 ? Kb : Vb);
    const float scale       = z == 0 ? (0.125f * LOG2E) : 1.0f;
    gemm_core<1>(xb, W, bias, C, H_, H_, scale, blockIdx.y * 128, blockIdx.x * 128);
}

__global__ __launch_bounds__(256) void gemm_out(
    const unsigned short* __restrict__ Ab, const unsigned short* __restrict__ Wo,
    const float* __restrict__ bo, float* __restrict__ out)
{
    gemm_core<0>(Ab, Wo, bo, out, H_, H_, 1.0f, blockIdx.y * 128, blockIdx.x * 128);
}

// ---------------------------------------------------------------------------
// MFMA flash attention — R14 (8-wave, 128-q) + double-buffered async staging.
// Grid 512 = exactly 2 blocks/CU; dbuf LDS 68KB still fits 2/CU -> free.
// Per tile: issue t+1 staging into buf 1-p at top (bins reg-load FIRST so
// its consume waits vmcnt(2), keeping staging in flight), compute on buf p,
// ds_write bins t+1, ONE barrier (drain lands after compute covered latency).
// ---------------------------------------------------------------------------
__global__ __launch_bounds__(512) void attn_mfma(
    const unsigned short* __restrict__ Qg, const unsigned short* __restrict__ Kg,
    const unsigned short* __restrict__ Vg, const unsigned char* __restrict__ bins,
    const float* __restrict__ demb, const float* __restrict__ abias,
    unsigned short* __restrict__ O)
{
    // ---- XCD swizzle (bijective; 512 = 8 XCD * 64) ----
    const int lin = blockIdx.x + 8 * blockIdx.y + 64 * blockIdx.z;
    const int swz = (lin & 7) * 64 + (lin >> 3);
    const int qt = swz & 7;          // 0..7 (128-q tiles)
    const int h  = (swz >> 3) & 7;
    const int b  = swz >> 6;
    const int q0 = qt * 128;
    const int t  = threadIdx.x;      // 0..511
    const int lane = t & 63;
    const int wave = t >> 6;         // 0..7
    const int l15 = lane & 15;
    const int lhi = lane >> 4;

    __shared__ unsigned short Ks[2][64 * 64];    // 2x8KB, XOR-swizzled rows
    __shared__ unsigned short Vs[2][64 * 64];    // 2x8KB, subtiled
    __shared__ unsigned short QPs[128 * 64];     // 16KB: Q prologue, then 8x2KB P
    __shared__ unsigned char  Bsh[2][128 * 80];  // 2x10KB: [q][k] bins tile

    // lane-register bias table (log2e domain); lane 63 = masked (-1.44e9)
    float dbl = -1.442695e9f;
    if (lane < 50) dbl = (demb[lane * NH_ + h] + abias[h]) * LOG2E;

    // ---- per-lane staging sources (pre-swizzled for linear LDS dest) ----
    const int C = wave * 64 + lane;
    const int kr = C >> 3, kc = C & 7;
    const unsigned short* ksrc =
        Kg + ((size_t)(b * N_) + kr) * H_ + h * HD_ + ((kc ^ (kr & 7)) * 8);
    const int vd16 = C >> 7, vrem = C & 127;
    const int vkrhi = vrem >> 3, vr2 = vrem & 7;
    const int vkr = vkrhi * 4 + (vr2 >> 1), vcc = vr2 & 1;
    const unsigned short* vsrc =
        Vg + ((size_t)(b * N_) + vkr) * H_ + h * HD_ + vd16 * 16 + vcc * 8;
    const unsigned char* bsrc = bins + ((size_t)(b * N_) + q0 + (t >> 2)) * N_ + (t & 3) * 16;
    const int bidx = (t >> 2) * 80 + (t & 3) * 16;

    // ---- stage Q (pre-scaled by 0.125*log2e), XOR-swizzled: 128 rows ----
    {
        const int qr = t >> 2;           // 0..127
        const int d0 = (t & 3) * 16;
        const unsigned short* src = Qg + ((size_t)(b * N_ + q0 + qr)) * H_ + h * HD_ + d0;
        #pragma unroll
        for (int cc = 0; cc < 2; ++cc) {
            const uint4 v = *(const uint4*)(src + 8 * cc);
            const int idx = (qr * 64 + d0 + 8 * cc) ^ ((qr & 7) << 3);
            *(uint4*)&QPs[idx] = v;
        }
    }
    // ---- tile-0 staging: bins reg first, then K/V direct-to-LDS ----
    const uint4 br0 = *(const uint4*)bsrc;
    __builtin_amdgcn_global_load_lds(GPTR(ksrc), LPTR(&Ks[0][(wave * 64) * 8]), 16, 0, 0);
    __builtin_amdgcn_global_load_lds(GPTR(vsrc), LPTR(&Vs[0][(wave * 64) * 8]), 16, 0, 0);
    __syncthreads();   // Q visible; tile-0 K/V landed

    // Q fragment (B-operand of swapped QK^T; wave owns rows wave*16..+15)
    short8 aq[2];
    {
        const int qrow = (wave << 4) + l15;
        #pragma unroll
        for (int ck = 0; ck < 2; ++ck) {
            const int kb = lhi * 8 + 32 * ck;
            const int idx = (qrow * 64 + kb) ^ ((qrow & 7) << 3);
            aq[ck] = *(const short8*)&QPs[idx];
        }
    }
    *(uint4*)&Bsh[0][bidx] = br0;
    __syncthreads();   // aq reads drained before QPs reused as P; Bsh[0] visible

    unsigned short* const Pw = &QPs[wave << 10];   // per-wave 2KB P region
    const unsigned trlane = (unsigned)(lhi << 8) + (unsigned)(l15 << 3);
    const unsigned vbase = (unsigned)(size_t)LPTR(&Vs[0][0]) + trlane;

    // per-lane softmax state for q = l15 (within this wave's 16-q group)
    float m = -INFINITY, lsum = 0.f;
    floatx4 o4[4];
    #pragma unroll
    for (int nd = 0; nd < 4; ++nd) o4[nd] = (floatx4)0.f;

    int p = 0;
    for (int tt = 0; tt < 16; ++tt) {
        // ---- issue tile t+1 staging into buf 1-p (bins reg-load FIRST) ----
        uint4 brn;
        if (tt < 15) {
            const size_t koff = (size_t)((tt + 1) * 64);
            brn = *(const uint4*)(bsrc + koff);
            __builtin_amdgcn_global_load_lds(GPTR(ksrc + koff * H_),
                LPTR(&Ks[1 - p][(wave * 64) * 8]), 16, 0, 0);
            __builtin_amdgcn_global_load_lds(GPTR(vsrc + koff * H_),
                LPTR(&Vs[1 - p][(wave * 64) * 8]), 16, 0, 0);
        }
        const unsigned short* Kp = &Ks[p][0];

        // ---- S^T = K (Q*0.125*log2e)^T : s4[kn][r] = S[q=l15][k=kn*16+lhi*4+r]
        floatx4 s4[4];
        __builtin_amdgcn_s_setprio(1);
        #pragma unroll
        for (int kn = 0; kn < 4; ++kn) {
            const int kcol = kn * 16 + l15;
            floatx4 acc = (floatx4)0.f;
            #pragma unroll
            for (int ck = 0; ck < 2; ++ck) {
                const int kb = lhi * 8 + 32 * ck;
                const int idx = (kcol * 64 + kb) ^ ((kcol & 7) << 3);
                const short8 bk = *(const short8*)&Kp[idx];
                acc = __builtin_amdgcn_mfma_f32_16x16x32_bf16(bk, aq[ck], acc, 0, 0, 0);
            }
            s4[kn] = acc;
        }
        __builtin_amdgcn_s_setprio(0);

        // ---- + distance bias: row q=l15 (wave group), contiguous k per kn ----
        #pragma unroll
        for (int kn = 0; kn < 4; ++kn) {
            const unsigned bb =
                *(const unsigned*)&Bsh[p][((wave << 4) + l15) * 80 + kn * 16 + (lhi << 2)];
            s4[kn][0] += __shfl(dbl, (int)(bb & 255u), 64);
            s4[kn][1] += __shfl(dbl, (int)((bb >> 8) & 255u), 64);
            s4[kn][2] += __shfl(dbl, (int)((bb >> 16) & 255u), 64);
            s4[kn][3] += __shfl(dbl, (int)(bb >> 24), 64);
        }

        // ---- online softmax: lane-local over 16 regs + 2-level shfl ----
        {
            float mx = s4[0][0];
            #pragma unroll
            for (int kn = 0; kn < 4; ++kn)
                #pragma unroll
                for (int r = 0; r < 4; ++r) mx = fmaxf(mx, s4[kn][r]);
            mx = fmaxf(mx, __shfl_xor(mx, 16, 64));
            mx = fmaxf(mx, __shfl_xor(mx, 32, 64));
            const float mnew = fmaxf(m, mx);
            float ts = 0.f;
            #pragma unroll
            for (int kn = 0; kn < 4; ++kn)
                #pragma unroll
                for (int r = 0; r < 4; ++r) {
                    const float pexp = EXP2(s4[kn][r] - mnew);
                    s4[kn][r] = pexp;
                    ts += pexp;
                }
            ts += __shfl_xor(ts, 16, 64);
            ts += __shfl_xor(ts, 32, 64);
            const float alpha = EXP2(m - mnew);
            lsum = lsum * alpha + ts;
            m = mnew;
            // broadcast alpha to O rows (q = lhi*4+r lives at lane l15=q)
            #pragma unroll
            for (int r = 0; r < 4; ++r) {
                const float ar = __shfl(alpha, lhi * 4 + r, 64);
                #pragma unroll
                for (int nd = 0; nd < 4; ++nd) o4[nd][r] *= ar;
            }
        }

        // ---- P[q=l15][k] -> LDS: 4 b64 writes at contiguous k ----
        #pragma unroll
        for (int kn = 0; kn < 4; ++kn) {
            short4_t pk;
            pk[0] = (short)f2bf(s4[kn][0]);
            pk[1] = (short)f2bf(s4[kn][1]);
            pk[2] = (short)f2bf(s4[kn][2]);
            pk[3] = (short)f2bf(s4[kn][3]);
            const int idx = (l15 * 64 + kn * 16 + (lhi << 2)) ^ ((l15 & 7) << 3);
            *(short4_t*)&Pw[idx] = pk;
        }

        // ---- PV: A = 2 direct b128 P reads; B = 16 V tr-reads ----
        short8 ap[2];
        #pragma unroll
        for (int ck = 0; ck < 2; ++ck) {
            const int idx = (l15 * 64 + ck * 32 + lhi * 8) ^ ((l15 & 7) << 3);
            ap[ck] = *(const short8*)&Pw[idx];
        }
        const unsigned vaddr = vbase + (unsigned)(p * 8192);
        short4_t v0l[4], v0h[4], v1l[4], v1h[4];
        TRB16(v0l[0], vaddr, "0");    TRB16(v0h[0], vaddr, "128");
        TRB16(v0l[1], vaddr, "2048"); TRB16(v0h[1], vaddr, "2176");
        TRB16(v0l[2], vaddr, "4096"); TRB16(v0h[2], vaddr, "4224");
        TRB16(v0l[3], vaddr, "6144"); TRB16(v0h[3], vaddr, "6272");
        TRB16(v1l[0], vaddr, "1024"); TRB16(v1h[0], vaddr, "1152");
        TRB16(v1l[1], vaddr, "3072"); TRB16(v1h[1], vaddr, "3200");
        TRB16(v1l[2], vaddr, "5120"); TRB16(v1h[2], vaddr, "5248");
        TRB16(v1l[3], vaddr, "7168"); TRB16(v1h[3], vaddr, "7296");
        asm volatile("s_waitcnt lgkmcnt(0)" ::: "memory");
        __builtin_amdgcn_sched_barrier(0);

        __builtin_amdgcn_s_setprio(1);
        #pragma unroll
        for (int nd = 0; nd < 4; ++nd) {
            const short8 bv0 = __builtin_shufflevector(v0l[nd], v0h[nd], 0, 1, 2, 3, 4, 5, 6, 7);
            o4[nd] = __builtin_amdgcn_mfma_f32_16x16x32_bf16(ap[0], bv0, o4[nd], 0, 0, 0);
            const short8 bv1 = __builtin_shufflevector(v1l[nd], v1h[nd], 0, 1, 2, 3, 4, 5, 6, 7);
            o4[nd] = __builtin_amdgcn_mfma_f32_16x16x32_bf16(ap[1], bv1, o4[nd], 0, 0, 0);
        }
        __builtin_amdgcn_s_setprio(0);

        // ---- bins t+1 -> alternate Bsh; ONE barrier drains staging ----
        if (tt < 15)
            *(uint4*)&Bsh[1 - p][bidx] = brn;
        __syncthreads();
        p ^= 1;
    }

    // ---- epilogue: pull lsum for q=lhi*4+r, normalize, write ----
    float inv[4];
    #pragma unroll
    for (int r = 0; r < 4; ++r) inv[r] = 1.f / __shfl(lsum, lhi * 4 + r, 64);
    #pragma unroll
    for (int nd = 0; nd < 4; ++nd) {
        const int d = nd * 16 + l15;
        #pragma unroll
        for (int r = 0; r < 4; ++r) {
            const int q = q0 + (wave << 4) + lhi * 4 + r;
            O[((size_t)(b * N_ + q)) * H_ + h * HD_ + d] = f2bf(o4[nd][r] * inv[r]);
        }
    }
}

// ---------------------------------------------------------------------------
extern "C" void kernel_launch(void* const* d_in, const int* in_sizes, int n_in,
                              void* d_out, int out_size, void* d_ws, size_t ws_size,
                              hipStream_t stream)
{
    const float* x    = (const float*)d_in[0];
    const float* dist = (const float*)d_in[1];
    const int*   mask = (const int*)d_in[2];
    const float* Wq   = (const float*)d_in[3];
    const float* bq   = (const float*)d_in[4];
    const float* Wk   = (const float*)d_in[5];
    const float* bk   = (const float*)d_in[6];
    const float* Wv   = (const float*)d_in[7];
    const float* bv   = (const float*)d_in[8];
    const float* Wo   = (const float*)d_in[9];
    const float* bo   = (const float*)d_in[10];
    const float* demb = (const float*)d_in[11];
    const float* ab   = (const float*)d_in[12];
    float* out = (float*)d_out;

    const size_t mat = (size_t)B_ * N_ * H_;         // 4,194,304
    const size_t wsz = (size_t)H_ * H_;              //   262,144

    unsigned short* blob = (unsigned short*)d_ws;
    unsigned short* xb  = blob;
    unsigned short* Wqb = blob + mat;
    unsigned short* Wkb = Wqb + wsz;
    unsigned short* Wvb = Wkb + wsz;
    unsigned short* Wob = Wvb + wsz;
    unsigned short* Qb  = Wob + wsz;
    unsigned short* Kb  = Qb + mat;
    unsigned short* Vb  = Kb + mat;
    unsigned short* Ab  = Vb + mat;
    unsigned char*  binsb = (unsigned char*)(Ab + mat);

    const dim3 blk(256);

    hipLaunchKernelGGL(prep_kernel, dim3(3328), blk, 0, stream,
                       x, Wq, Wk, Wv, Wo, blob, dist, mask, binsb);

    const dim3 qgrid(H_ / 128, (B_ * N_) / 128, 3);
    hipLaunchKernelGGL(gemm_qkv, qgrid, blk, 0, stream,
                       xb, Wqb, Wkb, Wvb, bq, bk, bv, Qb, Kb, Vb);

    const dim3 agrid(N_ / 128, NH_, B_);             // (8, 8, 8) = 512 blocks
    hipLaunchKernelGGL(attn_mfma, agrid, dim3(512), 0, stream,
                       Qb, Kb, Vb, binsb, demb, ab, Ab);

    const dim3 ogrid(H_ / 128, (B_ * N_) / 128, 1);
    hipLaunchKernelGGL(gemm_out, ogrid, blk, 0, stream, Ab, Wob, bo, out);
}